// Round 1
// baseline (870.889 us; speedup 1.0000x reference)
//
#include <hip/hip_runtime.h>
#include <math.h>

#define NN 4096
#define HH 256
#define BATCH 8
#define TOPK 32
#define LN_EPS 1e-5f

// ---------------------------------------------------------------------------
// K1: adj rows (8 per block) + per-row top-32 + softmax -> probs/idx
// grid 512 x 256 thr, 128 KiB dynamic LDS (8 rows x 4096 fp32 scores)
// ---------------------------------------------------------------------------
__global__ __launch_bounds__(256) void k_adj_topk(
    const float* __restrict__ n1, const float* __restrict__ n2,
    float* __restrict__ probs, int* __restrict__ pidx) {
  extern __shared__ float sc[];  // [8][4096]
  const int tid = threadIdx.x;
  const int r0 = blockIdx.x * 8;

  const float4* n1v = reinterpret_cast<const float4*>(n1) + (size_t)r0 * (HH / 4);

  // ---- compute scores: 4 chunks of 1024 cols, 4 cols/thread ----
  for (int chunk = 0; chunk < 4; ++chunk) {
    const int c0 = chunk * 1024 + tid;  // + w*256
    const float4* p0 = reinterpret_cast<const float4*>(n2) + (size_t)(c0      ) * (HH / 4);
    const float4* p1 = reinterpret_cast<const float4*>(n2) + (size_t)(c0 + 256) * (HH / 4);
    const float4* p2 = reinterpret_cast<const float4*>(n2) + (size_t)(c0 + 512) * (HH / 4);
    const float4* p3 = reinterpret_cast<const float4*>(n2) + (size_t)(c0 + 768) * (HH / 4);

    float acc[8][4];
#pragma unroll
    for (int r = 0; r < 8; ++r)
#pragma unroll
      for (int w = 0; w < 4; ++w) acc[r][w] = 0.f;

#pragma unroll 4
    for (int h4 = 0; h4 < HH / 4; ++h4) {
      const float4 q0 = p0[h4], q1 = p1[h4], q2 = p2[h4], q3 = p3[h4];
#pragma unroll
      for (int r = 0; r < 8; ++r) {
        const float4 a = n1v[r * (HH / 4) + h4];  // uniform addr -> scalar loads
        acc[r][0] = fmaf(a.x, q0.x, fmaf(a.y, q0.y, fmaf(a.z, q0.z, fmaf(a.w, q0.w, acc[r][0]))));
        acc[r][1] = fmaf(a.x, q1.x, fmaf(a.y, q1.y, fmaf(a.z, q1.z, fmaf(a.w, q1.w, acc[r][1]))));
        acc[r][2] = fmaf(a.x, q2.x, fmaf(a.y, q2.y, fmaf(a.z, q2.z, fmaf(a.w, q2.w, acc[r][2]))));
        acc[r][3] = fmaf(a.x, q3.x, fmaf(a.y, q3.y, fmaf(a.z, q3.z, fmaf(a.w, q3.w, acc[r][3]))));
      }
    }
#pragma unroll
    for (int r = 0; r < 8; ++r) {
      sc[r * NN + c0      ] = acc[r][0];
      sc[r * NN + c0 + 256] = acc[r][1];
      sc[r * NN + c0 + 512] = acc[r][2];
      sc[r * NN + c0 + 768] = acc[r][3];
    }
  }
  __syncthreads();

  // ---- per-wave top-32: wave w owns rows {2w, 2w+1}; no barriers needed ----
  const int wid = tid >> 6, lane = tid & 63;
#pragma unroll 1
  for (int rr = 0; rr < 2; ++rr) {
    const int r = wid * 2 + rr;
    const float* row = sc + r * NN;

    // initial per-lane top-2 over its 64-elem stripe (elements lane + 64j)
    float b1v = -1e30f, b2v = -1e30f;
    int b1i = NN, b2i = NN;
    for (int j = 0; j < 64; ++j) {
      const int ix = j * 64 + lane;
      const float v = row[ix];
      if (v > b1v) { b2v = b1v; b2i = b1i; b1v = v; b1i = ix; }
      else if (v > b2v) { b2v = v; b2i = ix; }
    }

    unsigned long long removed = 0ULL;
    float outv = -1e30f; int outi = 0;
    for (int it = 0; it < TOPK; ++it) {
      // wave argmax with lower-index tie-break (matches lax.top_k)
      float wv = b1v; int wi = b1i;
#pragma unroll
      for (int off = 32; off; off >>= 1) {
        const float ov = __shfl_xor(wv, off);
        const int   oi = __shfl_xor(wi, off);
        if (ov > wv || (ov == wv && oi < wi)) { wv = ov; wi = oi; }
      }
      if (lane == it) { outv = wv; outi = wi; }
      if ((wi & 63) == lane) {  // owner lane retires the winner
        removed |= 1ULL << (wi >> 6);
        b1v = b2v; b1i = b2i;
        b2v = -1e30f; b2i = NN;
        if (b1i == NN) {  // cached pair exhausted -> masked rescan
          b1v = -1e30f; b1i = NN;
          for (int j = 0; j < 64; ++j) {
            if ((removed >> j) & 1ULL) continue;
            const int ix = j * 64 + lane;
            const float v = row[ix];
            if (v > b1v) { b2v = b1v; b2i = b1i; b1v = v; b1i = ix; }
            else if (v > b2v) { b2v = v; b2i = ix; }
          }
        }
      }
    }
    // softmax over the 32 winners (held by lanes 0..31)
    float mx = outv;
#pragma unroll
    for (int off = 16; off; off >>= 1) mx = fmaxf(mx, __shfl_xor(mx, off, 32));
    const float e = expf(outv - mx);
    float sum = e;
#pragma unroll
    for (int off = 16; off; off >>= 1) sum += __shfl_xor(sum, off, 32);
    if (lane < TOPK) {
      probs[(size_t)(r0 + r) * TOPK + lane] = e / sum;
      pidx [(size_t)(r0 + r) * TOPK + lane] = outi;
    }
  }
}

// ---------------------------------------------------------------------------
// K2: gc gather + residual + LayerNorm1 -> tgt1 (stored in d_out)
// grid (4096, 8) x 256 thr
// ---------------------------------------------------------------------------
__global__ __launch_bounds__(256) void k_gather_ln1(
    const float* __restrict__ src, const float* __restrict__ tgt,
    const float* __restrict__ probs, const int* __restrict__ pidx,
    const float* __restrict__ lnw, const float* __restrict__ lnb,
    float* __restrict__ out) {
  __shared__ float lp[TOPK];
  __shared__ int li[TOPK];
  __shared__ float red[8];
  const int m = blockIdx.x, b = blockIdx.y;
  const int tid = threadIdx.x;
  if (tid < TOPK) { lp[tid] = probs[(size_t)m * TOPK + tid]; li[tid] = pidx[(size_t)m * TOPK + tid]; }
  __syncthreads();

  const float* sb = src + (size_t)b * NN * HH;
  float x = tgt[((size_t)b * NN + m) * HH + tid];
#pragma unroll
  for (int k = 0; k < TOPK; ++k) x = fmaf(lp[k], sb[(size_t)li[k] * HH + tid], x);

  float s = x, s2 = x * x;
#pragma unroll
  for (int off = 32; off; off >>= 1) { s += __shfl_down(s, off); s2 += __shfl_down(s2, off); }
  const int wid = tid >> 6, lane = tid & 63;
  if (!lane) { red[wid] = s; red[4 + wid] = s2; }
  __syncthreads();
  s  = red[0] + red[1] + red[2] + red[3];
  s2 = red[4] + red[5] + red[6] + red[7];
  const float mu = s * (1.f / HH);
  const float var = s2 * (1.f / HH) - mu * mu;
  const float rs = rsqrtf(var + LN_EPS);
  out[((size_t)b * NN + m) * HH + tid] = (x - mu) * rs * lnw[tid] + lnb[tid];
}

// ---------------------------------------------------------------------------
// K3/K4: C[M,256] = (relu?)(A[M,256] @ W[256,256]^T + bias)
// BM=BN=128, BK=32, 256 thr, 8x8 micro-tile. grid 512.
// ---------------------------------------------------------------------------
template <int RELU>
__global__ __launch_bounds__(256) void k_ffgemm(
    const float* __restrict__ A, const float* __restrict__ W,
    const float* __restrict__ bias, float* __restrict__ C) {
  __shared__ float As[32][128];
  __shared__ float Bs[32][128];
  const int tid = threadIdx.x;
  const int bn = blockIdx.x & 1;
  const int bm = blockIdx.x >> 1;
  const int tx = tid & 15, ty = tid >> 4;
  const float* Ab = A + (size_t)bm * 128 * HH;
  const float* Wb = W + (size_t)bn * 128 * HH;
  const int lrow = tid >> 3;        // 0..31
  const int lkk = (tid & 7) << 2;   // 0..28

  float acc[8][8] = {};
  for (int kt = 0; kt < 8; ++kt) {
    const int k0 = kt * 32;
#pragma unroll
    for (int i = 0; i < 4; ++i) {
      const float4 av = *reinterpret_cast<const float4*>(Ab + (size_t)(lrow + i * 32) * HH + k0 + lkk);
      As[lkk + 0][lrow + i * 32] = av.x;
      As[lkk + 1][lrow + i * 32] = av.y;
      As[lkk + 2][lrow + i * 32] = av.z;
      As[lkk + 3][lrow + i * 32] = av.w;
      const float4 bv = *reinterpret_cast<const float4*>(Wb + (size_t)(lrow + i * 32) * HH + k0 + lkk);
      Bs[lkk + 0][lrow + i * 32] = bv.x;
      Bs[lkk + 1][lrow + i * 32] = bv.y;
      Bs[lkk + 2][lrow + i * 32] = bv.z;
      Bs[lkk + 3][lrow + i * 32] = bv.w;
    }
    __syncthreads();
#pragma unroll
    for (int k = 0; k < 32; ++k) {
      float ar[8], br[8];
      *reinterpret_cast<float4*>(&ar[0]) = *reinterpret_cast<const float4*>(&As[k][ty * 8]);
      *reinterpret_cast<float4*>(&ar[4]) = *reinterpret_cast<const float4*>(&As[k][ty * 8 + 4]);
      *reinterpret_cast<float4*>(&br[0]) = *reinterpret_cast<const float4*>(&Bs[k][tx * 8]);
      *reinterpret_cast<float4*>(&br[4]) = *reinterpret_cast<const float4*>(&Bs[k][tx * 8 + 4]);
#pragma unroll
      for (int i = 0; i < 8; ++i)
#pragma unroll
        for (int j = 0; j < 8; ++j) acc[i][j] = fmaf(ar[i], br[j], acc[i][j]);
    }
    __syncthreads();
  }
#pragma unroll
  for (int i = 0; i < 8; ++i) {
    const size_t row = (size_t)bm * 128 + ty * 8 + i;
#pragma unroll
    for (int jj = 0; jj < 2; ++jj) {
      const int c0 = bn * 128 + tx * 8 + jj * 4;
      float4 v;
      v.x = acc[i][jj * 4 + 0] + bias[c0 + 0];
      v.y = acc[i][jj * 4 + 1] + bias[c0 + 1];
      v.z = acc[i][jj * 4 + 2] + bias[c0 + 2];
      v.w = acc[i][jj * 4 + 3] + bias[c0 + 3];
      if (RELU) {
        v.x = fmaxf(v.x, 0.f); v.y = fmaxf(v.y, 0.f);
        v.z = fmaxf(v.z, 0.f); v.w = fmaxf(v.w, 0.f);
      }
      *reinterpret_cast<float4*>(C + row * HH + c0) = v;
    }
  }
}

// ---------------------------------------------------------------------------
// K5: out = LN2(tgt1 + ff2). tgt1 lives in d_out; row-exclusive in-place safe.
// NOTE: no __restrict__ on tgt1/out — they alias.
// ---------------------------------------------------------------------------
__global__ __launch_bounds__(256) void k_res_ln2(
    const float* tgt1, const float* __restrict__ ff,
    const float* __restrict__ lnw, const float* __restrict__ lnb,
    float* out) {
  __shared__ float red[8];
  const size_t row = blockIdx.x;
  const int tid = threadIdx.x;
  const float x = tgt1[row * HH + tid] + ff[row * HH + tid];
  float s = x, s2 = x * x;
#pragma unroll
  for (int off = 32; off; off >>= 1) { s += __shfl_down(s, off); s2 += __shfl_down(s2, off); }
  const int wid = tid >> 6, lane = tid & 63;
  if (!lane) { red[wid] = s; red[4 + wid] = s2; }
  __syncthreads();
  s  = red[0] + red[1] + red[2] + red[3];
  s2 = red[4] + red[5] + red[6] + red[7];
  const float mu = s * (1.f / HH);
  const float var = s2 * (1.f / HH) - mu * mu;
  const float rs = rsqrtf(var + LN_EPS);
  out[row * HH + tid] = (x - mu) * rs * lnw[tid] + lnb[tid];
}

// ---------------------------------------------------------------------------
extern "C" void kernel_launch(void* const* d_in, const int* in_sizes, int n_in,
                              void* d_out, int out_size, void* d_ws, size_t ws_size,
                              hipStream_t stream) {
  const float* src  = (const float*)d_in[0];
  const float* tgt  = (const float*)d_in[1];
  const float* n1   = (const float*)d_in[2];
  const float* n2   = (const float*)d_in[3];
  const float* w1   = (const float*)d_in[4];
  const float* b1   = (const float*)d_in[5];
  const float* w2   = (const float*)d_in[6];
  const float* b2   = (const float*)d_in[7];
  const float* ln1w = (const float*)d_in[8];
  const float* ln1b = (const float*)d_in[9];
  const float* ln2w = (const float*)d_in[10];
  const float* ln2b = (const float*)d_in[11];
  float* out = (float*)d_out;

  // ws layout (floats): probs[N*K] | pidx[N*K] | ff1[B*N*H] | ff2[B*N*H]  (~66 MB)
  float* wsf   = (float*)d_ws;
  float* probs = wsf;
  int*   pidx  = (int*)(wsf + (size_t)NN * TOPK);
  float* ff1   = wsf + 2 * (size_t)NN * TOPK;
  float* ff2   = ff1 + (size_t)BATCH * NN * HH;

  hipFuncSetAttribute((const void*)k_adj_topk,
                      hipFuncAttributeMaxDynamicSharedMemorySize, 8 * NN * 4);

  k_adj_topk<<<NN / 8, 256, 8 * NN * 4, stream>>>(n1, n2, probs, pidx);

  dim3 g2(NN, BATCH);
  k_gather_ln1<<<g2, 256, 0, stream>>>(src, tgt, probs, pidx, ln1w, ln1b, out);

  const int gemm_grid = (BATCH * NN / 128) * (HH / 128);  // 512
  k_ffgemm<1><<<gemm_grid, 256, 0, stream>>>(out, w1, b1, ff1);
  k_ffgemm<0><<<gemm_grid, 256, 0, stream>>>(ff1, w2, b2, ff2);

  k_res_ln2<<<BATCH * NN, 256, 0, stream>>>(out, ff2, ln2w, ln2b, out);
}

// Round 2
// 409.231 us; speedup vs baseline: 2.1281x; 2.1281x over previous
//
#include <hip/hip_runtime.h>
#include <math.h>

#define NN 4096
#define HH 256
#define BATCH 8
#define TOPK 32
#define LN_EPS 1e-5f

// ---------------------------------------------------------------------------
// K1a: adj = n1 @ n2^T  (4096x4096x256 fp32)
// BM=BN=128, BK=32, 256 thr, 8x8 micro-tile. grid 1024.
// ---------------------------------------------------------------------------
__global__ __launch_bounds__(256) void k_adjgemm(
    const float* __restrict__ A, const float* __restrict__ W,
    float* __restrict__ C) {
  __shared__ float As[32][128];
  __shared__ float Bs[32][128];
  const int tid = threadIdx.x;
  const int bn = blockIdx.x & 31;
  const int bm = blockIdx.x >> 5;
  const int tx = tid & 15, ty = tid >> 4;
  const float* Ab = A + (size_t)bm * 128 * HH;
  const float* Wb = W + (size_t)bn * 128 * HH;
  const int lrow = tid >> 3;        // 0..31
  const int lkk = (tid & 7) << 2;   // 0..28

  float acc[8][8] = {};
  for (int kt = 0; kt < 8; ++kt) {
    const int k0 = kt * 32;
#pragma unroll
    for (int i = 0; i < 4; ++i) {
      const float4 av = *reinterpret_cast<const float4*>(Ab + (size_t)(lrow + i * 32) * HH + k0 + lkk);
      As[lkk + 0][lrow + i * 32] = av.x;
      As[lkk + 1][lrow + i * 32] = av.y;
      As[lkk + 2][lrow + i * 32] = av.z;
      As[lkk + 3][lrow + i * 32] = av.w;
      const float4 bv = *reinterpret_cast<const float4*>(Wb + (size_t)(lrow + i * 32) * HH + k0 + lkk);
      Bs[lkk + 0][lrow + i * 32] = bv.x;
      Bs[lkk + 1][lrow + i * 32] = bv.y;
      Bs[lkk + 2][lrow + i * 32] = bv.z;
      Bs[lkk + 3][lrow + i * 32] = bv.w;
    }
    __syncthreads();
#pragma unroll
    for (int k = 0; k < 32; ++k) {
      float ar[8], br[8];
      *reinterpret_cast<float4*>(&ar[0]) = *reinterpret_cast<const float4*>(&As[k][ty * 8]);
      *reinterpret_cast<float4*>(&ar[4]) = *reinterpret_cast<const float4*>(&As[k][ty * 8 + 4]);
      *reinterpret_cast<float4*>(&br[0]) = *reinterpret_cast<const float4*>(&Bs[k][tx * 8]);
      *reinterpret_cast<float4*>(&br[4]) = *reinterpret_cast<const float4*>(&Bs[k][tx * 8 + 4]);
#pragma unroll
      for (int i = 0; i < 8; ++i)
#pragma unroll
        for (int j = 0; j < 8; ++j) acc[i][j] = fmaf(ar[i], br[j], acc[i][j]);
    }
    __syncthreads();
  }
#pragma unroll
  for (int i = 0; i < 8; ++i) {
    const size_t row = (size_t)bm * 128 + ty * 8 + i;
#pragma unroll
    for (int jj = 0; jj < 2; ++jj) {
      const int c0 = bn * 128 + tx * 8 + jj * 4;
      float4 v;
      v.x = acc[i][jj * 4 + 0];
      v.y = acc[i][jj * 4 + 1];
      v.z = acc[i][jj * 4 + 2];
      v.w = acc[i][jj * 4 + 3];
      *reinterpret_cast<float4*>(C + row * NN + c0) = v;
    }
  }
}

// ---------------------------------------------------------------------------
// K1b: per-row top-32 + softmax. 1 wave per row, 4 rows/block, NO LDS.
// Reads adj straight from global (L2/L3-hot). grid 1024.
// ---------------------------------------------------------------------------
__global__ __launch_bounds__(256) void k_topk(
    const float* __restrict__ adj,
    float* __restrict__ probs, int* __restrict__ pidx) {
  const int tid = threadIdx.x;
  const int wid = tid >> 6, lane = tid & 63;
  const int r = blockIdx.x * 4 + wid;
  const float4* rp4 = reinterpret_cast<const float4*>(adj + (size_t)r * NN);

  // per-lane top-2 over its 64-elem stripe: elements ix = j*256 + lane*4 + t
  float b1v = -1e30f, b2v = -1e30f;
  int b1i = NN, b2i = NN;
#define UPD(v, ix)                                          \
  do {                                                      \
    const float _v = (v); const int _ix = (ix);             \
    if (_v > b1v) { b2v = b1v; b2i = b1i; b1v = _v; b1i = _ix; } \
    else if (_v > b2v) { b2v = _v; b2i = _ix; }             \
  } while (0)

#pragma unroll
  for (int j = 0; j < 16; ++j) {
    const float4 v = rp4[j * 64 + lane];
    const int ib = j * 256 + lane * 4;
    UPD(v.x, ib + 0); UPD(v.y, ib + 1); UPD(v.z, ib + 2); UPD(v.w, ib + 3);
  }

  unsigned long long removed = 0ULL;  // bit j*4+t per lane
  float outv = -1e30f; int outi = 0;
  for (int it = 0; it < TOPK; ++it) {
    // wave argmax, lower-index tie-break
    float wv = b1v; int wi = b1i;
#pragma unroll
    for (int off = 32; off; off >>= 1) {
      const float ov = __shfl_xor(wv, off);
      const int   oi = __shfl_xor(wi, off);
      if (ov > wv || (ov == wv && oi < wi)) { wv = ov; wi = oi; }
    }
    if (lane == it) { outv = wv; outi = wi; }
    if (((wi >> 2) & 63) == lane) {  // owner lane retires the winner
      removed |= 1ULL << (((wi >> 8) << 2) | (wi & 3));
      b1v = b2v; b1i = b2i;
      b2v = -1e30f; b2i = NN;
      if (b1i == NN) {  // cached pair exhausted -> masked rescan
        b1v = -1e30f; b1i = NN;
        for (int j = 0; j < 16; ++j) {
          const float4 v = rp4[j * 64 + lane];
          const int ib = j * 256 + lane * 4;
          const int rb = j * 4;
          if (!((removed >> (rb + 0)) & 1ULL)) UPD(v.x, ib + 0);
          if (!((removed >> (rb + 1)) & 1ULL)) UPD(v.y, ib + 1);
          if (!((removed >> (rb + 2)) & 1ULL)) UPD(v.z, ib + 2);
          if (!((removed >> (rb + 3)) & 1ULL)) UPD(v.w, ib + 3);
        }
      }
    }
  }
#undef UPD

  // softmax over the 32 winners (lanes 0..31)
  float mx = outv;
#pragma unroll
  for (int off = 16; off; off >>= 1) mx = fmaxf(mx, __shfl_xor(mx, off, 32));
  const float e = expf(outv - mx);
  float sum = e;
#pragma unroll
  for (int off = 16; off; off >>= 1) sum += __shfl_xor(sum, off, 32);
  if (lane < TOPK) {
    probs[(size_t)r * TOPK + lane] = e / sum;
    pidx [(size_t)r * TOPK + lane] = outi;
  }
}

// ---------------------------------------------------------------------------
// K2: gc gather + residual + LayerNorm1 -> tgt1 (stored in d_out)
// grid (4096, 8) x 256 thr
// ---------------------------------------------------------------------------
__global__ __launch_bounds__(256) void k_gather_ln1(
    const float* __restrict__ src, const float* __restrict__ tgt,
    const float* __restrict__ probs, const int* __restrict__ pidx,
    const float* __restrict__ lnw, const float* __restrict__ lnb,
    float* __restrict__ out) {
  __shared__ float lp[TOPK];
  __shared__ int li[TOPK];
  __shared__ float red[8];
  const int m = blockIdx.x, b = blockIdx.y;
  const int tid = threadIdx.x;
  if (tid < TOPK) { lp[tid] = probs[(size_t)m * TOPK + tid]; li[tid] = pidx[(size_t)m * TOPK + tid]; }
  __syncthreads();

  const float* sb = src + (size_t)b * NN * HH;
  float x = tgt[((size_t)b * NN + m) * HH + tid];
#pragma unroll
  for (int k = 0; k < TOPK; ++k) x = fmaf(lp[k], sb[(size_t)li[k] * HH + tid], x);

  float s = x, s2 = x * x;
#pragma unroll
  for (int off = 32; off; off >>= 1) { s += __shfl_down(s, off); s2 += __shfl_down(s2, off); }
  const int wid = tid >> 6, lane = tid & 63;
  if (!lane) { red[wid] = s; red[4 + wid] = s2; }
  __syncthreads();
  s  = red[0] + red[1] + red[2] + red[3];
  s2 = red[4] + red[5] + red[6] + red[7];
  const float mu = s * (1.f / HH);
  const float var = s2 * (1.f / HH) - mu * mu;
  const float rs = rsqrtf(var + LN_EPS);
  out[((size_t)b * NN + m) * HH + tid] = (x - mu) * rs * lnw[tid] + lnb[tid];
}

// ---------------------------------------------------------------------------
// K3/K4: C[M,256] = (relu?)(A[M,256] @ W[256,256]^T + bias)
// BM=BN=128, BK=32, 256 thr, 8x8 micro-tile. grid 512.
// ---------------------------------------------------------------------------
template <int RELU>
__global__ __launch_bounds__(256) void k_ffgemm(
    const float* __restrict__ A, const float* __restrict__ W,
    const float* __restrict__ bias, float* __restrict__ C) {
  __shared__ float As[32][128];
  __shared__ float Bs[32][128];
  const int tid = threadIdx.x;
  const int bn = blockIdx.x & 1;
  const int bm = blockIdx.x >> 1;
  const int tx = tid & 15, ty = tid >> 4;
  const float* Ab = A + (size_t)bm * 128 * HH;
  const float* Wb = W + (size_t)bn * 128 * HH;
  const int lrow = tid >> 3;        // 0..31
  const int lkk = (tid & 7) << 2;   // 0..28

  float acc[8][8] = {};
  for (int kt = 0; kt < 8; ++kt) {
    const int k0 = kt * 32;
#pragma unroll
    for (int i = 0; i < 4; ++i) {
      const float4 av = *reinterpret_cast<const float4*>(Ab + (size_t)(lrow + i * 32) * HH + k0 + lkk);
      As[lkk + 0][lrow + i * 32] = av.x;
      As[lkk + 1][lrow + i * 32] = av.y;
      As[lkk + 2][lrow + i * 32] = av.z;
      As[lkk + 3][lrow + i * 32] = av.w;
      const float4 bv = *reinterpret_cast<const float4*>(Wb + (size_t)(lrow + i * 32) * HH + k0 + lkk);
      Bs[lkk + 0][lrow + i * 32] = bv.x;
      Bs[lkk + 1][lrow + i * 32] = bv.y;
      Bs[lkk + 2][lrow + i * 32] = bv.z;
      Bs[lkk + 3][lrow + i * 32] = bv.w;
    }
    __syncthreads();
#pragma unroll
    for (int k = 0; k < 32; ++k) {
      float ar[8], br[8];
      *reinterpret_cast<float4*>(&ar[0]) = *reinterpret_cast<const float4*>(&As[k][ty * 8]);
      *reinterpret_cast<float4*>(&ar[4]) = *reinterpret_cast<const float4*>(&As[k][ty * 8 + 4]);
      *reinterpret_cast<float4*>(&br[0]) = *reinterpret_cast<const float4*>(&Bs[k][tx * 8]);
      *reinterpret_cast<float4*>(&br[4]) = *reinterpret_cast<const float4*>(&Bs[k][tx * 8 + 4]);
#pragma unroll
      for (int i = 0; i < 8; ++i)
#pragma unroll
        for (int j = 0; j < 8; ++j) acc[i][j] = fmaf(ar[i], br[j], acc[i][j]);
    }
    __syncthreads();
  }
#pragma unroll
  for (int i = 0; i < 8; ++i) {
    const size_t row = (size_t)bm * 128 + ty * 8 + i;
#pragma unroll
    for (int jj = 0; jj < 2; ++jj) {
      const int c0 = bn * 128 + tx * 8 + jj * 4;
      float4 v;
      v.x = acc[i][jj * 4 + 0] + bias[c0 + 0];
      v.y = acc[i][jj * 4 + 1] + bias[c0 + 1];
      v.z = acc[i][jj * 4 + 2] + bias[c0 + 2];
      v.w = acc[i][jj * 4 + 3] + bias[c0 + 3];
      if (RELU) {
        v.x = fmaxf(v.x, 0.f); v.y = fmaxf(v.y, 0.f);
        v.z = fmaxf(v.z, 0.f); v.w = fmaxf(v.w, 0.f);
      }
      *reinterpret_cast<float4*>(C + row * HH + c0) = v;
    }
  }
}

// ---------------------------------------------------------------------------
// K5: out = LN2(tgt1 + ff2). tgt1 lives in d_out; row-exclusive in-place safe.
// NOTE: no __restrict__ on tgt1/out — they alias.
// ---------------------------------------------------------------------------
__global__ __launch_bounds__(256) void k_res_ln2(
    const float* tgt1, const float* __restrict__ ff,
    const float* __restrict__ lnw, const float* __restrict__ lnb,
    float* out) {
  __shared__ float red[8];
  const size_t row = blockIdx.x;
  const int tid = threadIdx.x;
  const float x = tgt1[row * HH + tid] + ff[row * HH + tid];
  float s = x, s2 = x * x;
#pragma unroll
  for (int off = 32; off; off >>= 1) { s += __shfl_down(s, off); s2 += __shfl_down(s2, off); }
  const int wid = tid >> 6, lane = tid & 63;
  if (!lane) { red[wid] = s; red[4 + wid] = s2; }
  __syncthreads();
  s  = red[0] + red[1] + red[2] + red[3];
  s2 = red[4] + red[5] + red[6] + red[7];
  const float mu = s * (1.f / HH);
  const float var = s2 * (1.f / HH) - mu * mu;
  const float rs = rsqrtf(var + LN_EPS);
  out[row * HH + tid] = (x - mu) * rs * lnw[tid] + lnb[tid];
}

// ---------------------------------------------------------------------------
extern "C" void kernel_launch(void* const* d_in, const int* in_sizes, int n_in,
                              void* d_out, int out_size, void* d_ws, size_t ws_size,
                              hipStream_t stream) {
  const float* src  = (const float*)d_in[0];
  const float* tgt  = (const float*)d_in[1];
  const float* n1   = (const float*)d_in[2];
  const float* n2   = (const float*)d_in[3];
  const float* w1   = (const float*)d_in[4];
  const float* b1   = (const float*)d_in[5];
  const float* w2   = (const float*)d_in[6];
  const float* b2   = (const float*)d_in[7];
  const float* ln1w = (const float*)d_in[8];
  const float* ln1b = (const float*)d_in[9];
  const float* ln2w = (const float*)d_in[10];
  const float* ln2b = (const float*)d_in[11];
  float* out = (float*)d_out;

  // ws layout (floats): probs[N*K] | pidx[N*K] | region (64 MB):
  //   adj[N*N] lives there first (dead after k_topk), then ff1|ff2 overlay it.
  float* wsf   = (float*)d_ws;
  float* probs = wsf;
  int*   pidx  = (int*)(wsf + (size_t)NN * TOPK);
  float* base  = wsf + 2 * (size_t)NN * TOPK;
  float* adj   = base;
  float* ff1   = base;
  float* ff2   = base + (size_t)BATCH * NN * HH;

  k_adjgemm<<<(NN / 128) * (NN / 128), 256, 0, stream>>>(n1, n2, adj);
  k_topk<<<NN / 4, 256, 0, stream>>>(adj, probs, pidx);

  dim3 g2(NN, BATCH);
  k_gather_ln1<<<g2, 256, 0, stream>>>(src, tgt, probs, pidx, ln1w, ln1b, out);

  const int gemm_grid = (BATCH * NN / 128) * (HH / 128);  // 512
  k_ffgemm<1><<<gemm_grid, 256, 0, stream>>>(out, w1, b1, ff1);
  k_ffgemm<0><<<gemm_grid, 256, 0, stream>>>(ff1, w2, b2, ff2);

  k_res_ln2<<<BATCH * NN, 256, 0, stream>>>(out, ff2, ln2w, ln2b, out);
}

// Round 3
// 320.833 us; speedup vs baseline: 2.7145x; 1.2755x over previous
//
#include <hip/hip_runtime.h>
#include <math.h>

#define NN 4096
#define HH 256
#define BATCH 8
#define TOPK 32
#define LN_EPS 1e-5f

typedef float f32x4 __attribute__((ext_vector_type(4)));
typedef short bf16x8 __attribute__((ext_vector_type(8)));

__device__ __forceinline__ unsigned short f2bf(float x) {
  unsigned u = __float_as_uint(x);
  u += 0x7FFF + ((u >> 16) & 1);  // RNE
  return (unsigned short)(u >> 16);
}
__device__ __forceinline__ float bf2f(unsigned short h) {
  return __uint_as_float(((unsigned)h) << 16);
}

// stage one 16B LDS slot: 8 fp32 -> 8 bf16 (PART 0 = hi, 1 = residual lo)
template <int PART>
__device__ __forceinline__ void stage_slot(const float* __restrict__ src,
                                           unsigned short* dst) {
  const float4 v0 = *reinterpret_cast<const float4*>(src);
  const float4 v1 = *reinterpret_cast<const float4*>(src + 4);
  const float xs[8] = {v0.x, v0.y, v0.z, v0.w, v1.x, v1.y, v1.z, v1.w};
  union { unsigned short s[8]; uint4 q; } p;
#pragma unroll
  for (int e = 0; e < 8; ++e) {
    const unsigned short hi = f2bf(xs[e]);
    p.s[e] = (PART == 0) ? hi : f2bf(xs[e] - bf2f(hi));
  }
  *reinterpret_cast<uint4*>(dst) = p.q;
}

// one BK=32 K-step: 4x4 fragment MFMAs from [g:4][row:128][8] LDS tiles
__device__ __forceinline__ void mfma_tile(const unsigned short* Al,
                                          const unsigned short* Bl,
                                          int wr, int wc, int lane,
                                          f32x4 acc[4][4]) {
  const int g = lane >> 4, r = lane & 15;
  bf16x8 a[4], b[4];
#pragma unroll
  for (int i = 0; i < 4; ++i)
    a[i] = *reinterpret_cast<const bf16x8*>(Al + ((size_t)(g * 128 + wr * 64 + i * 16 + r)) * 8);
#pragma unroll
  for (int j = 0; j < 4; ++j)
    b[j] = *reinterpret_cast<const bf16x8*>(Bl + ((size_t)(g * 128 + wc * 64 + j * 16 + r)) * 8);
#pragma unroll
  for (int i = 0; i < 4; ++i)
#pragma unroll
    for (int j = 0; j < 4; ++j)
      acc[i][j] = __builtin_amdgcn_mfma_f32_16x16x32_bf16(a[i], b[j], acc[i][j], 0, 0, 0);
}

// ---------------------------------------------------------------------------
// K1a: adj = n1 @ n2^T via split-bf16 MFMA (virtual K=768: hh, hl, lh)
// 128x128 tile, 4 waves, grid 1024
// ---------------------------------------------------------------------------
__global__ __launch_bounds__(256) void k_adjgemm_mfma(
    const float* __restrict__ n1, const float* __restrict__ n2,
    float* __restrict__ adj) {
  __shared__ __align__(16) unsigned short Al[512 * 8];
  __shared__ __align__(16) unsigned short Bl[512 * 8];
  const int tid = threadIdx.x;
  const int lane = tid & 63, wid = tid >> 6;
  const int wr = wid >> 1, wc = wid & 1;
  const int bm = blockIdx.x >> 5, bn = blockIdx.x & 31;
  const int m0 = bm * 128, n0 = bn * 128;

  f32x4 acc[4][4];
#pragma unroll
  for (int i = 0; i < 4; ++i)
#pragma unroll
    for (int j = 0; j < 4; ++j) acc[i][j] = (f32x4){0.f, 0.f, 0.f, 0.f};

  const int row0 = tid & 127, g0 = tid >> 7;       // slot s0 = tid
  const int g1 = g0 + 2;                           // slot s1 = tid + 256 (same row)

  for (int t = 0; t < 24; ++t) {
    const int phase = t >> 3;          // 0: hi*hi, 1: hi*lo, 2: lo*hi
    const int kk = (t & 7) * 32;
    const bool aLo = (phase == 2);
    const bool bLo = (phase == 1);
    __syncthreads();  // previous compute done before overwriting LDS
    const float* a0 = n1 + (size_t)(m0 + row0) * HH + kk + g0 * 8;
    const float* a1 = n1 + (size_t)(m0 + row0) * HH + kk + g1 * 8;
    const float* b0 = n2 + (size_t)(n0 + row0) * HH + kk + g0 * 8;
    const float* b1 = n2 + (size_t)(n0 + row0) * HH + kk + g1 * 8;
    unsigned short* dA0 = Al + (size_t)tid * 8;
    unsigned short* dA1 = Al + (size_t)(tid + 256) * 8;
    unsigned short* dB0 = Bl + (size_t)tid * 8;
    unsigned short* dB1 = Bl + (size_t)(tid + 256) * 8;
    if (aLo) { stage_slot<1>(a0, dA0); stage_slot<1>(a1, dA1); }
    else     { stage_slot<0>(a0, dA0); stage_slot<0>(a1, dA1); }
    if (bLo) { stage_slot<1>(b0, dB0); stage_slot<1>(b1, dB1); }
    else     { stage_slot<0>(b0, dB0); stage_slot<0>(b1, dB1); }
    __syncthreads();
    mfma_tile(Al, Bl, wr, wc, lane, acc);
  }

  // C/D layout: col = lane&15, row = (lane>>4)*4 + q  [m89/m91-verified]
  const int crow = m0 + wr * 64 + (lane >> 4) * 4;
  const int ccol = n0 + wc * 64 + (lane & 15);
#pragma unroll
  for (int i = 0; i < 4; ++i)
#pragma unroll
    for (int j = 0; j < 4; ++j) {
      float* cp = adj + (size_t)(crow + i * 16) * NN + ccol + j * 16;
#pragma unroll
      for (int q = 0; q < 4; ++q) cp[(size_t)q * NN] = acc[i][j][q];
    }
}

// ---------------------------------------------------------------------------
// K3/K4: C[M,256] = (relu?)(A @ W^T + bias), bf16 MFMA, K=256
// 128x128 tile, grid 512
// ---------------------------------------------------------------------------
template <int RELU>
__global__ __launch_bounds__(256) void k_ffgemm_mfma(
    const float* __restrict__ A, const float* __restrict__ W,
    const float* __restrict__ bias, float* __restrict__ C) {
  __shared__ __align__(16) unsigned short Al[512 * 8];
  __shared__ __align__(16) unsigned short Bl[512 * 8];
  const int tid = threadIdx.x;
  const int lane = tid & 63, wid = tid >> 6;
  const int wr = wid >> 1, wc = wid & 1;
  const int bm = blockIdx.x >> 1, bn = blockIdx.x & 1;
  const int m0 = bm * 128, n0 = bn * 128;

  f32x4 acc[4][4];
#pragma unroll
  for (int i = 0; i < 4; ++i)
#pragma unroll
    for (int j = 0; j < 4; ++j) acc[i][j] = (f32x4){0.f, 0.f, 0.f, 0.f};

  const int row0 = tid & 127, g0 = tid >> 7;
  const int g1 = g0 + 2;

  for (int t = 0; t < 8; ++t) {
    const int kk = t * 32;
    __syncthreads();
    stage_slot<0>(A + (size_t)(m0 + row0) * HH + kk + g0 * 8, Al + (size_t)tid * 8);
    stage_slot<0>(A + (size_t)(m0 + row0) * HH + kk + g1 * 8, Al + (size_t)(tid + 256) * 8);
    stage_slot<0>(W + (size_t)(n0 + row0) * HH + kk + g0 * 8, Bl + (size_t)tid * 8);
    stage_slot<0>(W + (size_t)(n0 + row0) * HH + kk + g1 * 8, Bl + (size_t)(tid + 256) * 8);
    __syncthreads();
    mfma_tile(Al, Bl, wr, wc, lane, acc);
  }

  const int crow = m0 + wr * 64 + (lane >> 4) * 4;
  const int ccol = n0 + wc * 64 + (lane & 15);
#pragma unroll
  for (int i = 0; i < 4; ++i)
#pragma unroll
    for (int j = 0; j < 4; ++j) {
      const float bv = bias[ccol + j * 16];
      float* cp = C + (size_t)(crow + i * 16) * HH + ccol + j * 16;
#pragma unroll
      for (int q = 0; q < 4; ++q) {
        float v = acc[i][j][q] + bv;
        if (RELU) v = fmaxf(v, 0.f);
        cp[(size_t)q * HH] = v;
      }
    }
}

// ---------------------------------------------------------------------------
// K1b: per-row top-32 + softmax. 1 wave per row, 4 rows/block, NO LDS.
// ---------------------------------------------------------------------------
__global__ __launch_bounds__(256) void k_topk(
    const float* __restrict__ adj,
    float* __restrict__ probs, int* __restrict__ pidx) {
  const int tid = threadIdx.x;
  const int wid = tid >> 6, lane = tid & 63;
  const int r = blockIdx.x * 4 + wid;
  const float4* rp4 = reinterpret_cast<const float4*>(adj + (size_t)r * NN);

  float b1v = -1e30f, b2v = -1e30f;
  int b1i = NN, b2i = NN;
#define UPD(v, ix)                                          \
  do {                                                      \
    const float _v = (v); const int _ix = (ix);             \
    if (_v > b1v) { b2v = b1v; b2i = b1i; b1v = _v; b1i = _ix; } \
    else if (_v > b2v) { b2v = _v; b2i = _ix; }             \
  } while (0)

#pragma unroll
  for (int j = 0; j < 16; ++j) {
    const float4 v = rp4[j * 64 + lane];
    const int ib = j * 256 + lane * 4;
    UPD(v.x, ib + 0); UPD(v.y, ib + 1); UPD(v.z, ib + 2); UPD(v.w, ib + 3);
  }

  unsigned long long removed = 0ULL;
  float outv = -1e30f; int outi = 0;
  for (int it = 0; it < TOPK; ++it) {
    float wv = b1v; int wi = b1i;
#pragma unroll
    for (int off = 32; off; off >>= 1) {
      const float ov = __shfl_xor(wv, off);
      const int   oi = __shfl_xor(wi, off);
      if (ov > wv || (ov == wv && oi < wi)) { wv = ov; wi = oi; }
    }
    if (lane == it) { outv = wv; outi = wi; }
    if (((wi >> 2) & 63) == lane) {
      removed |= 1ULL << (((wi >> 8) << 2) | (wi & 3));
      b1v = b2v; b1i = b2i;
      b2v = -1e30f; b2i = NN;
      if (b1i == NN) {
        b1v = -1e30f; b1i = NN;
        for (int j = 0; j < 16; ++j) {
          const float4 v = rp4[j * 64 + lane];
          const int ib = j * 256 + lane * 4;
          const int rb = j * 4;
          if (!((removed >> (rb + 0)) & 1ULL)) UPD(v.x, ib + 0);
          if (!((removed >> (rb + 1)) & 1ULL)) UPD(v.y, ib + 1);
          if (!((removed >> (rb + 2)) & 1ULL)) UPD(v.z, ib + 2);
          if (!((removed >> (rb + 3)) & 1ULL)) UPD(v.w, ib + 3);
        }
      }
    }
  }
#undef UPD

  float mx = outv;
#pragma unroll
  for (int off = 16; off; off >>= 1) mx = fmaxf(mx, __shfl_xor(mx, off, 32));
  const float e = expf(outv - mx);
  float sum = e;
#pragma unroll
  for (int off = 16; off; off >>= 1) sum += __shfl_xor(sum, off, 32);
  if (lane < TOPK) {
    probs[(size_t)r * TOPK + lane] = e / sum;
    pidx [(size_t)r * TOPK + lane] = outi;
  }
}

// ---------------------------------------------------------------------------
// K2: gc gather + residual + LayerNorm1 -> tgt1 (stored in d_out)
// ---------------------------------------------------------------------------
__global__ __launch_bounds__(256) void k_gather_ln1(
    const float* __restrict__ src, const float* __restrict__ tgt,
    const float* __restrict__ probs, const int* __restrict__ pidx,
    const float* __restrict__ lnw, const float* __restrict__ lnb,
    float* __restrict__ out) {
  __shared__ float lp[TOPK];
  __shared__ int li[TOPK];
  __shared__ float red[8];
  const int m = blockIdx.x, b = blockIdx.y;
  const int tid = threadIdx.x;
  if (tid < TOPK) { lp[tid] = probs[(size_t)m * TOPK + tid]; li[tid] = pidx[(size_t)m * TOPK + tid]; }
  __syncthreads();

  const float* sb = src + (size_t)b * NN * HH;
  float x = tgt[((size_t)b * NN + m) * HH + tid];
#pragma unroll
  for (int k = 0; k < TOPK; ++k) x = fmaf(lp[k], sb[(size_t)li[k] * HH + tid], x);

  float s = x, s2 = x * x;
#pragma unroll
  for (int off = 32; off; off >>= 1) { s += __shfl_down(s, off); s2 += __shfl_down(s2, off); }
  const int wid = tid >> 6, lane = tid & 63;
  if (!lane) { red[wid] = s; red[4 + wid] = s2; }
  __syncthreads();
  s  = red[0] + red[1] + red[2] + red[3];
  s2 = red[4] + red[5] + red[6] + red[7];
  const float mu = s * (1.f / HH);
  const float var = s2 * (1.f / HH) - mu * mu;
  const float rs = rsqrtf(var + LN_EPS);
  out[((size_t)b * NN + m) * HH + tid] = (x - mu) * rs * lnw[tid] + lnb[tid];
}

// ---------------------------------------------------------------------------
// K5: out = LN2(tgt1 + ff2). tgt1 aliases out (row-exclusive, in-place safe).
// ---------------------------------------------------------------------------
__global__ __launch_bounds__(256) void k_res_ln2(
    const float* tgt1, const float* __restrict__ ff,
    const float* __restrict__ lnw, const float* __restrict__ lnb,
    float* out) {
  __shared__ float red[8];
  const size_t row = blockIdx.x;
  const int tid = threadIdx.x;
  const float x = tgt1[row * HH + tid] + ff[row * HH + tid];
  float s = x, s2 = x * x;
#pragma unroll
  for (int off = 32; off; off >>= 1) { s += __shfl_down(s, off); s2 += __shfl_down(s2, off); }
  const int wid = tid >> 6, lane = tid & 63;
  if (!lane) { red[wid] = s; red[4 + wid] = s2; }
  __syncthreads();
  s  = red[0] + red[1] + red[2] + red[3];
  s2 = red[4] + red[5] + red[6] + red[7];
  const float mu = s * (1.f / HH);
  const float var = s2 * (1.f / HH) - mu * mu;
  const float rs = rsqrtf(var + LN_EPS);
  out[row * HH + tid] = (x - mu) * rs * lnw[tid] + lnb[tid];
}

// ---------------------------------------------------------------------------
extern "C" void kernel_launch(void* const* d_in, const int* in_sizes, int n_in,
                              void* d_out, int out_size, void* d_ws, size_t ws_size,
                              hipStream_t stream) {
  const float* src  = (const float*)d_in[0];
  const float* tgt  = (const float*)d_in[1];
  const float* n1   = (const float*)d_in[2];
  const float* n2   = (const float*)d_in[3];
  const float* w1   = (const float*)d_in[4];
  const float* b1   = (const float*)d_in[5];
  const float* w2   = (const float*)d_in[6];
  const float* b2   = (const float*)d_in[7];
  const float* ln1w = (const float*)d_in[8];
  const float* ln1b = (const float*)d_in[9];
  const float* ln2w = (const float*)d_in[10];
  const float* ln2b = (const float*)d_in[11];
  float* out = (float*)d_out;

  // ws layout (floats): probs[N*K] | pidx[N*K] | region (64 MB):
  //   adj[N*N] first (dead after k_topk), then ff1|ff2 overlay it.  ~65 MB
  float* wsf   = (float*)d_ws;
  float* probs = wsf;
  int*   pidx  = (int*)(wsf + (size_t)NN * TOPK);
  float* base  = wsf + 2 * (size_t)NN * TOPK;
  float* adj   = base;
  float* ff1   = base;
  float* ff2   = base + (size_t)BATCH * NN * HH;

  k_adjgemm_mfma<<<(NN / 128) * (NN / 128), 256, 0, stream>>>(n1, n2, adj);
  k_topk<<<NN / 4, 256, 0, stream>>>(adj, probs, pidx);

  dim3 g2(NN, BATCH);
  k_gather_ln1<<<g2, 256, 0, stream>>>(src, tgt, probs, pidx, ln1w, ln1b, out);

  const int gemm_grid = (BATCH * NN / 128) * (HH / 128);  // 512
  k_ffgemm_mfma<1><<<gemm_grid, 256, 0, stream>>>(out, w1, b1, ff1);
  k_ffgemm_mfma<0><<<gemm_grid, 256, 0, stream>>>(ff1, w2, b2, ff2);

  k_res_ln2<<<BATCH * NN, 256, 0, stream>>>(out, ff2, ln2w, ln2b, out);
}

// Round 4
// 276.984 us; speedup vs baseline: 3.1442x; 1.1583x over previous
//
#include <hip/hip_runtime.h>
#include <math.h>

#define NN 4096
#define HH 256
#define BATCH 8
#define TOPK 32
#define LN_EPS 1e-5f

typedef float f32x4 __attribute__((ext_vector_type(4)));
typedef short bf16x8 __attribute__((ext_vector_type(8)));

__device__ __forceinline__ unsigned short f2bf(float x) {
  unsigned u = __float_as_uint(x);
  u += 0x7FFF + ((u >> 16) & 1);  // RNE
  return (unsigned short)(u >> 16);
}
__device__ __forceinline__ float bf2f(unsigned short h) {
  return __uint_as_float(((unsigned)h) << 16);
}

// stage one 16B LDS slot: 8 fp32 -> 8 bf16 (PART 0 = hi, 1 = residual lo)
template <int PART>
__device__ __forceinline__ void stage_slot(const float* __restrict__ src,
                                           unsigned short* dst) {
  const float4 v0 = *reinterpret_cast<const float4*>(src);
  const float4 v1 = *reinterpret_cast<const float4*>(src + 4);
  const float xs[8] = {v0.x, v0.y, v0.z, v0.w, v1.x, v1.y, v1.z, v1.w};
  union { unsigned short s[8]; uint4 q; } p;
#pragma unroll
  for (int e = 0; e < 8; ++e) {
    const unsigned short hi = f2bf(xs[e]);
    p.s[e] = (PART == 0) ? hi : f2bf(xs[e] - bf2f(hi));
  }
  *reinterpret_cast<uint4*>(dst) = p.q;
}

// one BK=32 K-step: 4x4 fragment MFMAs from [g:4][row:128][8] LDS tiles
__device__ __forceinline__ void mfma_tile(const unsigned short* Al,
                                          const unsigned short* Bl,
                                          int wr, int wc, int lane,
                                          f32x4 acc[4][4]) {
  const int g = lane >> 4, r = lane & 15;
  bf16x8 a[4], b[4];
#pragma unroll
  for (int i = 0; i < 4; ++i)
    a[i] = *reinterpret_cast<const bf16x8*>(Al + ((size_t)(g * 128 + wr * 64 + i * 16 + r)) * 8);
#pragma unroll
  for (int j = 0; j < 4; ++j)
    b[j] = *reinterpret_cast<const bf16x8*>(Bl + ((size_t)(g * 128 + wc * 64 + j * 16 + r)) * 8);
#pragma unroll
  for (int i = 0; i < 4; ++i)
#pragma unroll
    for (int j = 0; j < 4; ++j)
      acc[i][j] = __builtin_amdgcn_mfma_f32_16x16x32_bf16(a[i], b[j], acc[i][j], 0, 0, 0);
}

// ---------------------------------------------------------------------------
// K1a: adj = n1 @ n2^T via split-bf16 MFMA (virtual K=768: hh, hl, lh)
// 128x128 tile, 4 waves, grid 1024
// ---------------------------------------------------------------------------
__global__ __launch_bounds__(256) void k_adjgemm_mfma(
    const float* __restrict__ n1, const float* __restrict__ n2,
    float* __restrict__ adj) {
  __shared__ __align__(16) unsigned short Al[512 * 8];
  __shared__ __align__(16) unsigned short Bl[512 * 8];
  const int tid = threadIdx.x;
  const int lane = tid & 63, wid = tid >> 6;
  const int wr = wid >> 1, wc = wid & 1;
  const int bm = blockIdx.x >> 5, bn = blockIdx.x & 31;
  const int m0 = bm * 128, n0 = bn * 128;

  f32x4 acc[4][4];
#pragma unroll
  for (int i = 0; i < 4; ++i)
#pragma unroll
    for (int j = 0; j < 4; ++j) acc[i][j] = (f32x4){0.f, 0.f, 0.f, 0.f};

  const int row0 = tid & 127, g0 = tid >> 7;       // slot s0 = tid
  const int g1 = g0 + 2;                           // slot s1 = tid + 256 (same row)

  for (int t = 0; t < 24; ++t) {
    const int phase = t >> 3;          // 0: hi*hi, 1: hi*lo, 2: lo*hi
    const int kk = (t & 7) * 32;
    const bool aLo = (phase == 2);
    const bool bLo = (phase == 1);
    __syncthreads();  // previous compute done before overwriting LDS
    const float* a0 = n1 + (size_t)(m0 + row0) * HH + kk + g0 * 8;
    const float* a1 = n1 + (size_t)(m0 + row0) * HH + kk + g1 * 8;
    const float* b0 = n2 + (size_t)(n0 + row0) * HH + kk + g0 * 8;
    const float* b1 = n2 + (size_t)(n0 + row0) * HH + kk + g1 * 8;
    unsigned short* dA0 = Al + (size_t)tid * 8;
    unsigned short* dA1 = Al + (size_t)(tid + 256) * 8;
    unsigned short* dB0 = Bl + (size_t)tid * 8;
    unsigned short* dB1 = Bl + (size_t)(tid + 256) * 8;
    if (aLo) { stage_slot<1>(a0, dA0); stage_slot<1>(a1, dA1); }
    else     { stage_slot<0>(a0, dA0); stage_slot<0>(a1, dA1); }
    if (bLo) { stage_slot<1>(b0, dB0); stage_slot<1>(b1, dB1); }
    else     { stage_slot<0>(b0, dB0); stage_slot<0>(b1, dB1); }
    __syncthreads();
    mfma_tile(Al, Bl, wr, wc, lane, acc);
  }

  // C/D layout: col = lane&15, row = (lane>>4)*4 + q  [m89/m91-verified]
  const int crow = m0 + wr * 64 + (lane >> 4) * 4;
  const int ccol = n0 + wc * 64 + (lane & 15);
#pragma unroll
  for (int i = 0; i < 4; ++i)
#pragma unroll
    for (int j = 0; j < 4; ++j) {
      float* cp = adj + (size_t)(crow + i * 16) * NN + ccol + j * 16;
#pragma unroll
      for (int q = 0; q < 4; ++q) cp[(size_t)q * NN] = acc[i][j][q];
    }
}

// ---------------------------------------------------------------------------
// K3/K4: C[M,256] = (relu?)(A @ W^T + bias), bf16 MFMA, K=256
// 128x128 tile, grid 512
// ---------------------------------------------------------------------------
template <int RELU>
__global__ __launch_bounds__(256) void k_ffgemm_mfma(
    const float* __restrict__ A, const float* __restrict__ W,
    const float* __restrict__ bias, float* __restrict__ C) {
  __shared__ __align__(16) unsigned short Al[512 * 8];
  __shared__ __align__(16) unsigned short Bl[512 * 8];
  const int tid = threadIdx.x;
  const int lane = tid & 63, wid = tid >> 6;
  const int wr = wid >> 1, wc = wid & 1;
  const int bm = blockIdx.x >> 1, bn = blockIdx.x & 1;
  const int m0 = bm * 128, n0 = bn * 128;

  f32x4 acc[4][4];
#pragma unroll
  for (int i = 0; i < 4; ++i)
#pragma unroll
    for (int j = 0; j < 4; ++j) acc[i][j] = (f32x4){0.f, 0.f, 0.f, 0.f};

  const int row0 = tid & 127, g0 = tid >> 7;
  const int g1 = g0 + 2;

  for (int t = 0; t < 8; ++t) {
    const int kk = t * 32;
    __syncthreads();
    stage_slot<0>(A + (size_t)(m0 + row0) * HH + kk + g0 * 8, Al + (size_t)tid * 8);
    stage_slot<0>(A + (size_t)(m0 + row0) * HH + kk + g1 * 8, Al + (size_t)(tid + 256) * 8);
    stage_slot<0>(W + (size_t)(n0 + row0) * HH + kk + g0 * 8, Bl + (size_t)tid * 8);
    stage_slot<0>(W + (size_t)(n0 + row0) * HH + kk + g1 * 8, Bl + (size_t)(tid + 256) * 8);
    __syncthreads();
    mfma_tile(Al, Bl, wr, wc, lane, acc);
  }

  const int crow = m0 + wr * 64 + (lane >> 4) * 4;
  const int ccol = n0 + wc * 64 + (lane & 15);
#pragma unroll
  for (int i = 0; i < 4; ++i)
#pragma unroll
    for (int j = 0; j < 4; ++j) {
      const float bv = bias[ccol + j * 16];
      float* cp = C + (size_t)(crow + i * 16) * HH + ccol + j * 16;
#pragma unroll
      for (int q = 0; q < 4; ++q) {
        float v = acc[i][j][q] + bv;
        if (RELU) v = fmaxf(v, 0.f);
        cp[(size_t)q * HH] = v;
      }
    }
}

// ---------------------------------------------------------------------------
// K1b: per-row top-32 + softmax. 1 wave/row, 4 rows/block, no LDS.
// u64 keys (valbits<<32 | N-1-idx): unique, tie-break = lower index.
// Per-lane sorted top-4 cache; winners retire in descending key order, so
// the exact rescan filter is just (key < last_winner_key).
// ---------------------------------------------------------------------------
__global__ __launch_bounds__(256) void k_topk(
    const float* __restrict__ adj,
    float* __restrict__ probs, int* __restrict__ pidx) {
  const int tid = threadIdx.x;
  const int wid = tid >> 6, lane = tid & 63;
  const int r = blockIdx.x * 4 + wid;
  const float4* rp4 = reinterpret_cast<const float4*>(adj + (size_t)r * NN);

  // adj values are strictly positive -> float bits are order-monotone
#define KEY(v, ix) ((((unsigned long long)__float_as_uint(v)) << 32) | \
                    (unsigned)(NN - 1 - (ix)))

  unsigned long long k1 = 0, k2 = 0, k3 = 0, k4 = 0;  // sorted desc; 0 = empty
#define INS(v, ix)                                              \
  do {                                                          \
    const unsigned long long _k = KEY(v, ix);                   \
    if (_k > k4) {                                              \
      if (_k > k1)      { k4 = k3; k3 = k2; k2 = k1; k1 = _k; } \
      else if (_k > k2) { k4 = k3; k3 = k2; k2 = _k; }          \
      else if (_k > k3) { k4 = k3; k3 = _k; }                   \
      else              { k4 = _k; }                            \
    }                                                           \
  } while (0)

#pragma unroll
  for (int j = 0; j < 16; ++j) {
    const float4 v = rp4[j * 64 + lane];
    const int ib = j * 256 + lane * 4;
    INS(v.x, ib + 0); INS(v.y, ib + 1); INS(v.z, ib + 2); INS(v.w, ib + 3);
  }

  unsigned long long win = 0;
  for (int it = 0; it < TOPK; ++it) {
    unsigned long long w = k1;
#pragma unroll
    for (int off = 32; off; off >>= 1) {
      const unsigned long long o = __shfl_xor(w, off);
      if (o > w) w = o;
    }
    if (lane == it) win = w;
    if (w == k1) {  // unique owner retires the winner
      k1 = k2; k2 = k3; k3 = k4; k4 = 0;
      if (k1 == 0ULL) {  // top-4 cache exhausted (rare): exact masked rebuild
        for (int j = 0; j < 16; ++j) {
          const float4 v = rp4[j * 64 + lane];
          const int ib = j * 256 + lane * 4;
          if (KEY(v.x, ib + 0) < w) INS(v.x, ib + 0);
          if (KEY(v.y, ib + 1) < w) INS(v.y, ib + 1);
          if (KEY(v.z, ib + 2) < w) INS(v.z, ib + 2);
          if (KEY(v.w, ib + 3) < w) INS(v.w, ib + 3);
        }
      }
    }
  }
#undef INS
#undef KEY

  // softmax over the 32 winners (lanes 0..31 hold them)
  const float outv = __uint_as_float((unsigned)(win >> 32));
  float mx = outv;
#pragma unroll
  for (int off = 16; off; off >>= 1) mx = fmaxf(mx, __shfl_xor(mx, off, 32));
  const float e = expf(outv - mx);
  float sum = e;
#pragma unroll
  for (int off = 16; off; off >>= 1) sum += __shfl_xor(sum, off, 32);
  if (lane < TOPK) {
    probs[(size_t)r * TOPK + lane] = e / sum;
    pidx [(size_t)r * TOPK + lane] = NN - 1 - (int)(win & 0xFFFFFFFFu);
  }
}

// ---------------------------------------------------------------------------
// K2: gc gather + residual + LayerNorm1 -> tgt1 (stored in d_out)
// ---------------------------------------------------------------------------
__global__ __launch_bounds__(256) void k_gather_ln1(
    const float* __restrict__ src, const float* __restrict__ tgt,
    const float* __restrict__ probs, const int* __restrict__ pidx,
    const float* __restrict__ lnw, const float* __restrict__ lnb,
    float* __restrict__ out) {
  __shared__ float lp[TOPK];
  __shared__ int li[TOPK];
  __shared__ float red[8];
  const int m = blockIdx.x, b = blockIdx.y;
  const int tid = threadIdx.x;
  if (tid < TOPK) { lp[tid] = probs[(size_t)m * TOPK + tid]; li[tid] = pidx[(size_t)m * TOPK + tid]; }
  __syncthreads();

  const float* sb = src + (size_t)b * NN * HH;
  float x = tgt[((size_t)b * NN + m) * HH + tid];
#pragma unroll
  for (int k = 0; k < TOPK; ++k) x = fmaf(lp[k], sb[(size_t)li[k] * HH + tid], x);

  float s = x, s2 = x * x;
#pragma unroll
  for (int off = 32; off; off >>= 1) { s += __shfl_down(s, off); s2 += __shfl_down(s2, off); }
  const int wid = tid >> 6, lane = tid & 63;
  if (!lane) { red[wid] = s; red[4 + wid] = s2; }
  __syncthreads();
  s  = red[0] + red[1] + red[2] + red[3];
  s2 = red[4] + red[5] + red[6] + red[7];
  const float mu = s * (1.f / HH);
  const float var = s2 * (1.f / HH) - mu * mu;
  const float rs = rsqrtf(var + LN_EPS);
  out[((size_t)b * NN + m) * HH + tid] = (x - mu) * rs * lnw[tid] + lnb[tid];
}

// ---------------------------------------------------------------------------
// K5: out = LN2(tgt1 + ff2). tgt1 aliases out (row-exclusive, in-place safe).
// ---------------------------------------------------------------------------
__global__ __launch_bounds__(256) void k_res_ln2(
    const float* tgt1, const float* __restrict__ ff,
    const float* __restrict__ lnw, const float* __restrict__ lnb,
    float* out) {
  __shared__ float red[8];
  const size_t row = blockIdx.x;
  const int tid = threadIdx.x;
  const float x = tgt1[row * HH + tid] + ff[row * HH + tid];
  float s = x, s2 = x * x;
#pragma unroll
  for (int off = 32; off; off >>= 1) { s += __shfl_down(s, off); s2 += __shfl_down(s2, off); }
  const int wid = tid >> 6, lane = tid & 63;
  if (!lane) { red[wid] = s; red[4 + wid] = s2; }
  __syncthreads();
  s  = red[0] + red[1] + red[2] + red[3];
  s2 = red[4] + red[5] + red[6] + red[7];
  const float mu = s * (1.f / HH);
  const float var = s2 * (1.f / HH) - mu * mu;
  const float rs = rsqrtf(var + LN_EPS);
  out[row * HH + tid] = (x - mu) * rs * lnw[tid] + lnb[tid];
}

// ---------------------------------------------------------------------------
extern "C" void kernel_launch(void* const* d_in, const int* in_sizes, int n_in,
                              void* d_out, int out_size, void* d_ws, size_t ws_size,
                              hipStream_t stream) {
  const float* src  = (const float*)d_in[0];
  const float* tgt  = (const float*)d_in[1];
  const float* n1   = (const float*)d_in[2];
  const float* n2   = (const float*)d_in[3];
  const float* w1   = (const float*)d_in[4];
  const float* b1   = (const float*)d_in[5];
  const float* w2   = (const float*)d_in[6];
  const float* b2   = (const float*)d_in[7];
  const float* ln1w = (const float*)d_in[8];
  const float* ln1b = (const float*)d_in[9];
  const float* ln2w = (const float*)d_in[10];
  const float* ln2b = (const float*)d_in[11];
  float* out = (float*)d_out;

  // ws layout (floats): probs[N*K] | pidx[N*K] | region (64 MB):
  //   adj[N*N] first (dead after k_topk), then ff1|ff2 overlay it.  ~65 MB
  float* wsf   = (float*)d_ws;
  float* probs = wsf;
  int*   pidx  = (int*)(wsf + (size_t)NN * TOPK);
  float* base  = wsf + 2 * (size_t)NN * TOPK;
  float* adj   = base;
  float* ff1   = base;
  float* ff2   = base + (size_t)BATCH * NN * HH;

  k_adjgemm_mfma<<<(NN / 128) * (NN / 128), 256, 0, stream>>>(n1, n2, adj);
  k_topk<<<NN / 4, 256, 0, stream>>>(adj, probs, pidx);

  dim3 g2(NN, BATCH);
  k_gather_ln1<<<g2, 256, 0, stream>>>(src, tgt, probs, pidx, ln1w, ln1b, out);

  const int gemm_grid = (BATCH * NN / 128) * (HH / 128);  // 512
  k_ffgemm_mfma<1><<<gemm_grid, 256, 0, stream>>>(out, w1, b1, ff1);
  k_ffgemm_mfma<0><<<gemm_grid, 256, 0, stream>>>(ff1, w2, b2, ff2);

  k_res_ln2<<<BATCH * NN, 256, 0, stream>>>(out, ff2, ln2w, ln2b, out);
}

// Round 5
// 228.512 us; speedup vs baseline: 3.8111x; 1.2121x over previous
//
#include <hip/hip_runtime.h>
#include <math.h>

#define NN 4096
#define HH 256
#define BATCH 8
#define TOPK 32
#define LN_EPS 1e-5f

typedef float f32x4 __attribute__((ext_vector_type(4)));
typedef short bf16x8 __attribute__((ext_vector_type(8)));

__device__ __forceinline__ unsigned short f2bf(float x) {
  unsigned u = __float_as_uint(x);
  u += 0x7FFF + ((u >> 16) & 1);  // RNE
  return (unsigned short)(u >> 16);
}
__device__ __forceinline__ float bf2f(unsigned short h) {
  return __uint_as_float(((unsigned)h) << 16);
}

// async global->LDS, 16B per lane; LDS dest is wave-uniform base + lane*16
__device__ __forceinline__ void gload16(const void* g, void* l) {
  __builtin_amdgcn_global_load_lds(
      (const __attribute__((address_space(1))) void*)g,
      (__attribute__((address_space(3))) void*)l, 16, 0, 0);
}

// stage one 16B LDS slot: 8 fp32 -> 8 bf16 (PART 0 = hi, 1 = residual lo)
template <int PART>
__device__ __forceinline__ void stage_slot(const float* __restrict__ src,
                                           unsigned short* dst) {
  const float4 v0 = *reinterpret_cast<const float4*>(src);
  const float4 v1 = *reinterpret_cast<const float4*>(src + 4);
  const float xs[8] = {v0.x, v0.y, v0.z, v0.w, v1.x, v1.y, v1.z, v1.w};
  union { unsigned short s[8]; uint4 q; } p;
#pragma unroll
  for (int e = 0; e < 8; ++e) {
    const unsigned short hi = f2bf(xs[e]);
    p.s[e] = (PART == 0) ? hi : f2bf(xs[e] - bf2f(hi));
  }
  *reinterpret_cast<uint4*>(dst) = p.q;
}

// one BK=32 K-step: 4x4 fragment MFMAs from [g:4][row:128][8] LDS tiles
__device__ __forceinline__ void mfma_tile(const unsigned short* Al,
                                          const unsigned short* Bl,
                                          int wr, int wc, int lane,
                                          f32x4 acc[4][4]) {
  const int g = lane >> 4, r = lane & 15;
  bf16x8 a[4], b[4];
#pragma unroll
  for (int i = 0; i < 4; ++i)
    a[i] = *reinterpret_cast<const bf16x8*>(Al + ((size_t)(g * 128 + wr * 64 + i * 16 + r)) * 8);
#pragma unroll
  for (int j = 0; j < 4; ++j)
    b[j] = *reinterpret_cast<const bf16x8*>(Bl + ((size_t)(g * 128 + wc * 64 + j * 16 + r)) * 8);
#pragma unroll
  for (int i = 0; i < 4; ++i)
#pragma unroll
    for (int j = 0; j < 4; ++j)
      acc[i][j] = __builtin_amdgcn_mfma_f32_16x16x32_bf16(a[i], b[j], acc[i][j], 0, 0, 0);
}

// ---------------------------------------------------------------------------
// K0: split-bf16 pack of n1/n2 into GEMM LDS slot order.
// pack[bm][step][slot=g*128+(row&127)][e], steps 0..7 = hi, 8..15 = lo.
// grid (512, 2) x 256: 32 consecutive threads read one full 1KB row.
// ---------------------------------------------------------------------------
__global__ __launch_bounds__(256) void k_pack(
    const float* __restrict__ n1, const float* __restrict__ n2,
    unsigned short* __restrict__ apack, unsigned short* __restrict__ bpack) {
  const int u = blockIdx.x * 256 + threadIdx.x;  // 0..131071
  const float* srcm = blockIdx.y ? n2 : n1;
  unsigned short* dstm = blockIdx.y ? bpack : apack;
  const int row = u >> 5, kg = u & 31;
  const int st = kg >> 2, g = kg & 3;
  const int bm = row >> 7, slot = g * 128 + (row & 127);

  const float4 v0 = *reinterpret_cast<const float4*>(srcm + (size_t)row * HH + kg * 8);
  const float4 v1 = *reinterpret_cast<const float4*>(srcm + (size_t)row * HH + kg * 8 + 4);
  const float xs[8] = {v0.x, v0.y, v0.z, v0.w, v1.x, v1.y, v1.z, v1.w};
  union { unsigned short s[8]; uint4 q; } hi, lo;
#pragma unroll
  for (int e = 0; e < 8; ++e) {
    hi.s[e] = f2bf(xs[e]);
    lo.s[e] = f2bf(xs[e] - bf2f(hi.s[e]));
  }
  *reinterpret_cast<uint4*>(dstm + ((size_t)(bm * 16 + st) * 512 + slot) * 8) = hi.q;
  *reinterpret_cast<uint4*>(dstm + ((size_t)(bm * 16 + 8 + st) * 512 + slot) * 8) = lo.q;
}

// ---------------------------------------------------------------------------
// K1a: adj = n1 @ n2^T from packs via global_load_lds (m97 structure).
// 128x128 tile, 4 waves, 24 virtual K-steps (hh, hl, lh). grid 1024.
// ---------------------------------------------------------------------------
__global__ __launch_bounds__(256) void k_adjgemm_pk(
    const unsigned short* __restrict__ apack,
    const unsigned short* __restrict__ bpack,
    float* __restrict__ adj) {
  __shared__ __align__(16) unsigned short Al[512 * 8];
  __shared__ __align__(16) unsigned short Bl[512 * 8];
  const int tid = threadIdx.x;
  const int lane = tid & 63, wid = tid >> 6;
  const int wr = wid >> 1, wc = wid & 1;
  const int bm = blockIdx.x >> 5, bn = blockIdx.x & 31;
  const int m0 = bm * 128, n0 = bn * 128;

  f32x4 acc[4][4];
#pragma unroll
  for (int i = 0; i < 4; ++i)
#pragma unroll
    for (int j = 0; j < 4; ++j) acc[i][j] = (f32x4){0.f, 0.f, 0.f, 0.f};

  // wave-uniform LDS bases (wave w owns slots w*64.. and 256+w*64..)
  unsigned short* lA0 = Al + (size_t)(wid * 64) * 8;
  unsigned short* lA1 = Al + (size_t)(256 + wid * 64) * 8;
  unsigned short* lB0 = Bl + (size_t)(wid * 64) * 8;
  unsigned short* lB1 = Bl + (size_t)(256 + wid * 64) * 8;

  for (int t = 0; t < 24; ++t) {
    const int phase = t >> 3, st = t & 7;  // 0: hi*hi, 1: hi*lo, 2: lo*hi
    const int ta = (phase == 2) ? 8 + st : st;
    const int tb = (phase == 1) ? 8 + st : st;
    const unsigned short* ga = apack + (size_t)(bm * 16 + ta) * 4096;
    const unsigned short* gb = bpack + (size_t)(bn * 16 + tb) * 4096;
    __syncthreads();  // previous compute done before overwriting LDS
    gload16(ga + (size_t)tid * 8, lA0);
    gload16(ga + (size_t)(256 + tid) * 8, lA1);
    gload16(gb + (size_t)tid * 8, lB0);
    gload16(gb + (size_t)(256 + tid) * 8, lB1);
    __syncthreads();  // drains vmcnt -> LDS tiles ready
    mfma_tile(Al, Bl, wr, wc, lane, acc);
  }

  // C/D layout: col = lane&15, row = (lane>>4)*4 + q  [m89/m91-verified]
  const int crow = m0 + wr * 64 + (lane >> 4) * 4;
  const int ccol = n0 + wc * 64 + (lane & 15);
#pragma unroll
  for (int i = 0; i < 4; ++i)
#pragma unroll
    for (int j = 0; j < 4; ++j) {
      float* cp = adj + (size_t)(crow + i * 16) * NN + ccol + j * 16;
#pragma unroll
      for (int q = 0; q < 4; ++q) cp[(size_t)q * NN] = acc[i][j][q];
    }
}

// ---------------------------------------------------------------------------
// K3/K4: C[M,256] = (relu?)(A @ W^T + bias), bf16 MFMA, K=256
// 128x128 tile, grid 512
// ---------------------------------------------------------------------------
template <int RELU>
__global__ __launch_bounds__(256) void k_ffgemm_mfma(
    const float* __restrict__ A, const float* __restrict__ W,
    const float* __restrict__ bias, float* __restrict__ C) {
  __shared__ __align__(16) unsigned short Al[512 * 8];
  __shared__ __align__(16) unsigned short Bl[512 * 8];
  const int tid = threadIdx.x;
  const int lane = tid & 63, wid = tid >> 6;
  const int wr = wid >> 1, wc = wid & 1;
  const int bm = blockIdx.x >> 1, bn = blockIdx.x & 1;
  const int m0 = bm * 128, n0 = bn * 128;

  f32x4 acc[4][4];
#pragma unroll
  for (int i = 0; i < 4; ++i)
#pragma unroll
    for (int j = 0; j < 4; ++j) acc[i][j] = (f32x4){0.f, 0.f, 0.f, 0.f};

  const int row0 = tid & 127, g0 = tid >> 7;
  const int g1 = g0 + 2;

  for (int t = 0; t < 8; ++t) {
    const int kk = t * 32;
    __syncthreads();
    stage_slot<0>(A + (size_t)(m0 + row0) * HH + kk + g0 * 8, Al + (size_t)tid * 8);
    stage_slot<0>(A + (size_t)(m0 + row0) * HH + kk + g1 * 8, Al + (size_t)(tid + 256) * 8);
    stage_slot<0>(W + (size_t)(n0 + row0) * HH + kk + g0 * 8, Bl + (size_t)tid * 8);
    stage_slot<0>(W + (size_t)(n0 + row0) * HH + kk + g1 * 8, Bl + (size_t)(tid + 256) * 8);
    __syncthreads();
    mfma_tile(Al, Bl, wr, wc, lane, acc);
  }

  const int crow = m0 + wr * 64 + (lane >> 4) * 4;
  const int ccol = n0 + wc * 64 + (lane & 15);
#pragma unroll
  for (int i = 0; i < 4; ++i)
#pragma unroll
    for (int j = 0; j < 4; ++j) {
      const float bv = bias[ccol + j * 16];
      float* cp = C + (size_t)(crow + i * 16) * HH + ccol + j * 16;
#pragma unroll
      for (int q = 0; q < 4; ++q) {
        float v = acc[i][j][q] + bv;
        if (RELU) v = fmaxf(v, 0.f);
        cp[(size_t)q * HH] = v;
      }
    }
}

// ---------------------------------------------------------------------------
// K1b: per-row top-32 + softmax. 1 wave/row, 4 rows/block, no LDS.
// u64 keys (valbits<<32 | N-1-idx): unique, tie-break = lower index.
// ---------------------------------------------------------------------------
__global__ __launch_bounds__(256) void k_topk(
    const float* __restrict__ adj,
    float* __restrict__ probs, int* __restrict__ pidx) {
  const int tid = threadIdx.x;
  const int wid = tid >> 6, lane = tid & 63;
  const int r = blockIdx.x * 4 + wid;
  const float4* rp4 = reinterpret_cast<const float4*>(adj + (size_t)r * NN);

#define KEY(v, ix) ((((unsigned long long)__float_as_uint(v)) << 32) | \
                    (unsigned)(NN - 1 - (ix)))

  unsigned long long k1 = 0, k2 = 0, k3 = 0, k4 = 0;  // sorted desc; 0 = empty
#define INS(v, ix)                                              \
  do {                                                          \
    const unsigned long long _k = KEY(v, ix);                   \
    if (_k > k4) {                                              \
      if (_k > k1)      { k4 = k3; k3 = k2; k2 = k1; k1 = _k; } \
      else if (_k > k2) { k4 = k3; k3 = k2; k2 = _k; }          \
      else if (_k > k3) { k4 = k3; k3 = _k; }                   \
      else              { k4 = _k; }                            \
    }                                                           \
  } while (0)

#pragma unroll
  for (int j = 0; j < 16; ++j) {
    const float4 v = rp4[j * 64 + lane];
    const int ib = j * 256 + lane * 4;
    INS(v.x, ib + 0); INS(v.y, ib + 1); INS(v.z, ib + 2); INS(v.w, ib + 3);
  }

  unsigned long long win = 0;
  for (int it = 0; it < TOPK; ++it) {
    unsigned long long w = k1;
#pragma unroll
    for (int off = 32; off; off >>= 1) {
      const unsigned long long o = __shfl_xor(w, off);
      if (o > w) w = o;
    }
    if (lane == it) win = w;
    if (w == k1) {  // unique owner retires the winner
      k1 = k2; k2 = k3; k3 = k4; k4 = 0;
      if (k1 == 0ULL) {  // top-4 cache exhausted (rare): exact masked rebuild
        for (int j = 0; j < 16; ++j) {
          const float4 v = rp4[j * 64 + lane];
          const int ib = j * 256 + lane * 4;
          if (KEY(v.x, ib + 0) < w) INS(v.x, ib + 0);
          if (KEY(v.y, ib + 1) < w) INS(v.y, ib + 1);
          if (KEY(v.z, ib + 2) < w) INS(v.z, ib + 2);
          if (KEY(v.w, ib + 3) < w) INS(v.w, ib + 3);
        }
      }
    }
  }
#undef INS
#undef KEY

  const float outv = __uint_as_float((unsigned)(win >> 32));
  float mx = outv;
#pragma unroll
  for (int off = 16; off; off >>= 1) mx = fmaxf(mx, __shfl_xor(mx, off, 32));
  const float e = expf(outv - mx);
  float sum = e;
#pragma unroll
  for (int off = 16; off; off >>= 1) sum += __shfl_xor(sum, off, 32);
  if (lane < TOPK) {
    probs[(size_t)r * TOPK + lane] = e / sum;
    pidx [(size_t)r * TOPK + lane] = NN - 1 - (int)(win & 0xFFFFFFFFu);
  }
}

// ---------------------------------------------------------------------------
// K2: gc gather + residual + LayerNorm1 -> tgt1 (stored in d_out)
// ---------------------------------------------------------------------------
__global__ __launch_bounds__(256) void k_gather_ln1(
    const float* __restrict__ src, const float* __restrict__ tgt,
    const float* __restrict__ probs, const int* __restrict__ pidx,
    const float* __restrict__ lnw, const float* __restrict__ lnb,
    float* __restrict__ out) {
  __shared__ float lp[TOPK];
  __shared__ int li[TOPK];
  __shared__ float red[8];
  const int m = blockIdx.x, b = blockIdx.y;
  const int tid = threadIdx.x;
  if (tid < TOPK) { lp[tid] = probs[(size_t)m * TOPK + tid]; li[tid] = pidx[(size_t)m * TOPK + tid]; }
  __syncthreads();

  const float* sb = src + (size_t)b * NN * HH;
  float x = tgt[((size_t)b * NN + m) * HH + tid];
#pragma unroll
  for (int k = 0; k < TOPK; ++k) x = fmaf(lp[k], sb[(size_t)li[k] * HH + tid], x);

  float s = x, s2 = x * x;
#pragma unroll
  for (int off = 32; off; off >>= 1) { s += __shfl_down(s, off); s2 += __shfl_down(s2, off); }
  const int wid = tid >> 6, lane = tid & 63;
  if (!lane) { red[wid] = s; red[4 + wid] = s2; }
  __syncthreads();
  s  = red[0] + red[1] + red[2] + red[3];
  s2 = red[4] + red[5] + red[6] + red[7];
  const float mu = s * (1.f / HH);
  const float var = s2 * (1.f / HH) - mu * mu;
  const float rs = rsqrtf(var + LN_EPS);
  out[((size_t)b * NN + m) * HH + tid] = (x - mu) * rs * lnw[tid] + lnb[tid];
}

// ---------------------------------------------------------------------------
// K5: out = LN2(tgt1 + ff2). tgt1 aliases out (row-exclusive, in-place safe).
// ---------------------------------------------------------------------------
__global__ __launch_bounds__(256) void k_res_ln2(
    const float* tgt1, const float* __restrict__ ff,
    const float* __restrict__ lnw, const float* __restrict__ lnb,
    float* out) {
  __shared__ float red[8];
  const size_t row = blockIdx.x;
  const int tid = threadIdx.x;
  const float x = tgt1[row * HH + tid] + ff[row * HH + tid];
  float s = x, s2 = x * x;
#pragma unroll
  for (int off = 32; off; off >>= 1) { s += __shfl_down(s, off); s2 += __shfl_down(s2, off); }
  const int wid = tid >> 6, lane = tid & 63;
  if (!lane) { red[wid] = s; red[4 + wid] = s2; }
  __syncthreads();
  s  = red[0] + red[1] + red[2] + red[3];
  s2 = red[4] + red[5] + red[6] + red[7];
  const float mu = s * (1.f / HH);
  const float var = s2 * (1.f / HH) - mu * mu;
  const float rs = rsqrtf(var + LN_EPS);
  out[row * HH + tid] = (x - mu) * rs * lnw[tid] + lnb[tid];
}

// ---------------------------------------------------------------------------
extern "C" void kernel_launch(void* const* d_in, const int* in_sizes, int n_in,
                              void* d_out, int out_size, void* d_ws, size_t ws_size,
                              hipStream_t stream) {
  const float* src  = (const float*)d_in[0];
  const float* tgt  = (const float*)d_in[1];
  const float* n1   = (const float*)d_in[2];
  const float* n2   = (const float*)d_in[3];
  const float* w1   = (const float*)d_in[4];
  const float* b1   = (const float*)d_in[5];
  const float* w2   = (const float*)d_in[6];
  const float* b2   = (const float*)d_in[7];
  const float* ln1w = (const float*)d_in[8];
  const float* ln1b = (const float*)d_in[9];
  const float* ln2w = (const float*)d_in[10];
  const float* ln2b = (const float*)d_in[11];
  float* out = (float*)d_out;

  // ws (floats): probs[N*K] | pidx[N*K] | region (64 MB, adj then ff1|ff2)
  //              | apack (4 MB bf16) | bpack (4 MB bf16)   total ~73 MB
  float* wsf   = (float*)d_ws;
  float* probs = wsf;
  int*   pidx  = (int*)(wsf + (size_t)NN * TOPK);
  float* base  = wsf + 2 * (size_t)NN * TOPK;
  float* adj   = base;
  float* ff1   = base;
  float* ff2   = base + (size_t)BATCH * NN * HH;
  unsigned short* apack = (unsigned short*)(base + (size_t)NN * NN);
  unsigned short* bpack = apack + (size_t)32 * 16 * 512 * 8;

  dim3 gp(512, 2);
  k_pack<<<gp, 256, 0, stream>>>(n1, n2, apack, bpack);
  k_adjgemm_pk<<<(NN / 128) * (NN / 128), 256, 0, stream>>>(apack, bpack, adj);
  k_topk<<<NN / 4, 256, 0, stream>>>(adj, probs, pidx);

  dim3 g2(NN, BATCH);
  k_gather_ln1<<<g2, 256, 0, stream>>>(src, tgt, probs, pidx, ln1w, ln1b, out);

  const int gemm_grid = (BATCH * NN / 128) * (HH / 128);  // 512
  k_ffgemm_mfma<1><<<gemm_grid, 256, 0, stream>>>(out, w1, b1, ff1);
  k_ffgemm_mfma<0><<<gemm_grid, 256, 0, stream>>>(ff1, w2, b2, ff2);

  k_res_ln2<<<BATCH * NN, 256, 0, stream>>>(out, ff2, ln2w, ln2b, out);
}

// Round 6
// 217.225 us; speedup vs baseline: 4.0092x; 1.0520x over previous
//
#include <hip/hip_runtime.h>
#include <math.h>

#define NN 4096
#define HH 256
#define BATCH 8
#define TOPK 32
#define LN_EPS 1e-5f

typedef float f32x4 __attribute__((ext_vector_type(4)));
typedef short bf16x8 __attribute__((ext_vector_type(8)));

__device__ __forceinline__ unsigned short f2bf(float x) {
  unsigned u = __float_as_uint(x);
  u += 0x7FFF + ((u >> 16) & 1);  // RNE
  return (unsigned short)(u >> 16);
}
__device__ __forceinline__ float bf2f(unsigned short h) {
  return __uint_as_float(((unsigned)h) << 16);
}

// async global->LDS, 16B per lane; LDS dest is wave-uniform base + lane*16
__device__ __forceinline__ void gload16(const void* g, void* l) {
  __builtin_amdgcn_global_load_lds(
      (const __attribute__((address_space(1))) void*)g,
      (__attribute__((address_space(3))) void*)l, 16, 0, 0);
}

// stage one 16B LDS slot: 8 fp32 -> 8 bf16 (PART 0 = hi, 1 = residual lo)
template <int PART>
__device__ __forceinline__ void stage_slot(const float* __restrict__ src,
                                           unsigned short* dst) {
  const float4 v0 = *reinterpret_cast<const float4*>(src);
  const float4 v1 = *reinterpret_cast<const float4*>(src + 4);
  const float xs[8] = {v0.x, v0.y, v0.z, v0.w, v1.x, v1.y, v1.z, v1.w};
  union { unsigned short s[8]; uint4 q; } p;
#pragma unroll
  for (int e = 0; e < 8; ++e) {
    const unsigned short hi = f2bf(xs[e]);
    p.s[e] = (PART == 0) ? hi : f2bf(xs[e] - bf2f(hi));
  }
  *reinterpret_cast<uint4*>(dst) = p.q;
}

// one BK=32 K-step: 4x4 fragment MFMAs from [g:4][row:128][8] LDS tiles
__device__ __forceinline__ void mfma_tile(const unsigned short* Al,
                                          const unsigned short* Bl,
                                          int wr, int wc, int lane,
                                          f32x4 acc[4][4]) {
  const int g = lane >> 4, r = lane & 15;
  bf16x8 a[4], b[4];
#pragma unroll
  for (int i = 0; i < 4; ++i)
    a[i] = *reinterpret_cast<const bf16x8*>(Al + ((size_t)(g * 128 + wr * 64 + i * 16 + r)) * 8);
#pragma unroll
  for (int j = 0; j < 4; ++j)
    b[j] = *reinterpret_cast<const bf16x8*>(Bl + ((size_t)(g * 128 + wc * 64 + j * 16 + r)) * 8);
#pragma unroll
  for (int i = 0; i < 4; ++i)
#pragma unroll
    for (int j = 0; j < 4; ++j)
      acc[i][j] = __builtin_amdgcn_mfma_f32_16x16x32_bf16(a[i], b[j], acc[i][j], 0, 0, 0);
}

// ---------------------------------------------------------------------------
// K0: split-bf16 pack of n1/n2 into GEMM LDS slot order.
// pack[bm][step][slot=g*128+(row&127)][e], steps 0..7 = hi, 8..15 = lo.
// ---------------------------------------------------------------------------
__global__ __launch_bounds__(256) void k_pack(
    const float* __restrict__ n1, const float* __restrict__ n2,
    unsigned short* __restrict__ apack, unsigned short* __restrict__ bpack) {
  const int u = blockIdx.x * 256 + threadIdx.x;  // 0..131071
  const float* srcm = blockIdx.y ? n2 : n1;
  unsigned short* dstm = blockIdx.y ? bpack : apack;
  const int row = u >> 5, kg = u & 31;
  const int st = kg >> 2, g = kg & 3;
  const int bm = row >> 7, slot = g * 128 + (row & 127);

  const float4 v0 = *reinterpret_cast<const float4*>(srcm + (size_t)row * HH + kg * 8);
  const float4 v1 = *reinterpret_cast<const float4*>(srcm + (size_t)row * HH + kg * 8 + 4);
  const float xs[8] = {v0.x, v0.y, v0.z, v0.w, v1.x, v1.y, v1.z, v1.w};
  union { unsigned short s[8]; uint4 q; } hi, lo;
#pragma unroll
  for (int e = 0; e < 8; ++e) {
    hi.s[e] = f2bf(xs[e]);
    lo.s[e] = f2bf(xs[e] - bf2f(hi.s[e]));
  }
  *reinterpret_cast<uint4*>(dstm + ((size_t)(bm * 16 + st) * 512 + slot) * 8) = hi.q;
  *reinterpret_cast<uint4*>(dstm + ((size_t)(bm * 16 + 8 + st) * 512 + slot) * 8) = lo.q;
}

// ---------------------------------------------------------------------------
// K0b: src fp32 -> bf16 (same [b][n][h] layout). Runs AFTER k_topk: its
// output overlays the dead adj buffer.
// ---------------------------------------------------------------------------
__global__ __launch_bounds__(256) void k_srcpack(
    const float* __restrict__ src, unsigned short* __restrict__ s16) {
  const size_t i = ((size_t)blockIdx.x * 256 + threadIdx.x) * 8;
  const float4 v0 = *reinterpret_cast<const float4*>(src + i);
  const float4 v1 = *reinterpret_cast<const float4*>(src + i + 4);
  const float xs[8] = {v0.x, v0.y, v0.z, v0.w, v1.x, v1.y, v1.z, v1.w};
  union { unsigned short s[8]; uint4 q; } p;
#pragma unroll
  for (int e = 0; e < 8; ++e) p.s[e] = f2bf(xs[e]);
  *reinterpret_cast<uint4*>(s16 + i) = p.q;
}

// ---------------------------------------------------------------------------
// K1a: adj = n1 @ n2^T from packs via global_load_lds (m97 structure).
// 128x128 tile, 4 waves, 24 virtual K-steps (hh, hl, lh). grid 1024.
// ---------------------------------------------------------------------------
__global__ __launch_bounds__(256) void k_adjgemm_pk(
    const unsigned short* __restrict__ apack,
    const unsigned short* __restrict__ bpack,
    float* __restrict__ adj) {
  __shared__ __align__(16) unsigned short Al[512 * 8];
  __shared__ __align__(16) unsigned short Bl[512 * 8];
  const int tid = threadIdx.x;
  const int lane = tid & 63, wid = tid >> 6;
  const int wr = wid >> 1, wc = wid & 1;
  const int bm = blockIdx.x >> 5, bn = blockIdx.x & 31;
  const int m0 = bm * 128, n0 = bn * 128;

  f32x4 acc[4][4];
#pragma unroll
  for (int i = 0; i < 4; ++i)
#pragma unroll
    for (int j = 0; j < 4; ++j) acc[i][j] = (f32x4){0.f, 0.f, 0.f, 0.f};

  unsigned short* lA0 = Al + (size_t)(wid * 64) * 8;
  unsigned short* lA1 = Al + (size_t)(256 + wid * 64) * 8;
  unsigned short* lB0 = Bl + (size_t)(wid * 64) * 8;
  unsigned short* lB1 = Bl + (size_t)(256 + wid * 64) * 8;

  for (int t = 0; t < 24; ++t) {
    const int phase = t >> 3, st = t & 7;  // 0: hi*hi, 1: hi*lo, 2: lo*hi
    const int ta = (phase == 2) ? 8 + st : st;
    const int tb = (phase == 1) ? 8 + st : st;
    const unsigned short* ga = apack + (size_t)(bm * 16 + ta) * 4096;
    const unsigned short* gb = bpack + (size_t)(bn * 16 + tb) * 4096;
    __syncthreads();
    gload16(ga + (size_t)tid * 8, lA0);
    gload16(ga + (size_t)(256 + tid) * 8, lA1);
    gload16(gb + (size_t)tid * 8, lB0);
    gload16(gb + (size_t)(256 + tid) * 8, lB1);
    __syncthreads();
    mfma_tile(Al, Bl, wr, wc, lane, acc);
  }

  const int crow = m0 + wr * 64 + (lane >> 4) * 4;
  const int ccol = n0 + wc * 64 + (lane & 15);
#pragma unroll
  for (int i = 0; i < 4; ++i)
#pragma unroll
    for (int j = 0; j < 4; ++j) {
      float* cp = adj + (size_t)(crow + i * 16) * NN + ccol + j * 16;
#pragma unroll
      for (int q = 0; q < 4; ++q) cp[(size_t)q * NN] = acc[i][j][q];
    }
}

// ---------------------------------------------------------------------------
// K3/K4: C[M,256] = (relu?)(A @ W^T + bias), bf16 MFMA, K=256
// ---------------------------------------------------------------------------
template <int RELU>
__global__ __launch_bounds__(256) void k_ffgemm_mfma(
    const float* __restrict__ A, const float* __restrict__ W,
    const float* __restrict__ bias, float* __restrict__ C) {
  __shared__ __align__(16) unsigned short Al[512 * 8];
  __shared__ __align__(16) unsigned short Bl[512 * 8];
  const int tid = threadIdx.x;
  const int lane = tid & 63, wid = tid >> 6;
  const int wr = wid >> 1, wc = wid & 1;
  const int bm = blockIdx.x >> 1, bn = blockIdx.x & 1;
  const int m0 = bm * 128, n0 = bn * 128;

  f32x4 acc[4][4];
#pragma unroll
  for (int i = 0; i < 4; ++i)
#pragma unroll
    for (int j = 0; j < 4; ++j) acc[i][j] = (f32x4){0.f, 0.f, 0.f, 0.f};

  const int row0 = tid & 127, g0 = tid >> 7;
  const int g1 = g0 + 2;

  for (int t = 0; t < 8; ++t) {
    const int kk = t * 32;
    __syncthreads();
    stage_slot<0>(A + (size_t)(m0 + row0) * HH + kk + g0 * 8, Al + (size_t)tid * 8);
    stage_slot<0>(A + (size_t)(m0 + row0) * HH + kk + g1 * 8, Al + (size_t)(tid + 256) * 8);
    stage_slot<0>(W + (size_t)(n0 + row0) * HH + kk + g0 * 8, Bl + (size_t)tid * 8);
    stage_slot<0>(W + (size_t)(n0 + row0) * HH + kk + g1 * 8, Bl + (size_t)(tid + 256) * 8);
    __syncthreads();
    mfma_tile(Al, Bl, wr, wc, lane, acc);
  }

  const int crow = m0 + wr * 64 + (lane >> 4) * 4;
  const int ccol = n0 + wc * 64 + (lane & 15);
#pragma unroll
  for (int i = 0; i < 4; ++i)
#pragma unroll
    for (int j = 0; j < 4; ++j) {
      const float bv = bias[ccol + j * 16];
      float* cp = C + (size_t)(crow + i * 16) * HH + ccol + j * 16;
#pragma unroll
      for (int q = 0; q < 4; ++q) {
        float v = acc[i][j][q] + bv;
        if (RELU) v = fmaxf(v, 0.f);
        cp[(size_t)q * HH] = v;
      }
    }
}

// ---------------------------------------------------------------------------
// K1b: per-row top-32 + softmax. 1 wave/row, 4 rows/block, no LDS.
// ---------------------------------------------------------------------------
__global__ __launch_bounds__(256) void k_topk(
    const float* __restrict__ adj,
    float* __restrict__ probs, int* __restrict__ pidx) {
  const int tid = threadIdx.x;
  const int wid = tid >> 6, lane = tid & 63;
  const int r = blockIdx.x * 4 + wid;
  const float4* rp4 = reinterpret_cast<const float4*>(adj + (size_t)r * NN);

#define KEY(v, ix) ((((unsigned long long)__float_as_uint(v)) << 32) | \
                    (unsigned)(NN - 1 - (ix)))

  unsigned long long k1 = 0, k2 = 0, k3 = 0, k4 = 0;  // sorted desc; 0 = empty
#define INS(v, ix)                                              \
  do {                                                          \
    const unsigned long long _k = KEY(v, ix);                   \
    if (_k > k4) {                                              \
      if (_k > k1)      { k4 = k3; k3 = k2; k2 = k1; k1 = _k; } \
      else if (_k > k2) { k4 = k3; k3 = k2; k2 = _k; }          \
      else if (_k > k3) { k4 = k3; k3 = _k; }                   \
      else              { k4 = _k; }                            \
    }                                                           \
  } while (0)

#pragma unroll
  for (int j = 0; j < 16; ++j) {
    const float4 v = rp4[j * 64 + lane];
    const int ib = j * 256 + lane * 4;
    INS(v.x, ib + 0); INS(v.y, ib + 1); INS(v.z, ib + 2); INS(v.w, ib + 3);
  }

  unsigned long long win = 0;
  for (int it = 0; it < TOPK; ++it) {
    unsigned long long w = k1;
#pragma unroll
    for (int off = 32; off; off >>= 1) {
      const unsigned long long o = __shfl_xor(w, off);
      if (o > w) w = o;
    }
    if (lane == it) win = w;
    if (w == k1) {  // unique owner retires the winner
      k1 = k2; k2 = k3; k3 = k4; k4 = 0;
      if (k1 == 0ULL) {  // top-4 cache exhausted (rare): exact masked rebuild
        for (int j = 0; j < 16; ++j) {
          const float4 v = rp4[j * 64 + lane];
          const int ib = j * 256 + lane * 4;
          if (KEY(v.x, ib + 0) < w) INS(v.x, ib + 0);
          if (KEY(v.y, ib + 1) < w) INS(v.y, ib + 1);
          if (KEY(v.z, ib + 2) < w) INS(v.z, ib + 2);
          if (KEY(v.w, ib + 3) < w) INS(v.w, ib + 3);
        }
      }
    }
  }
#undef INS
#undef KEY

  const float outv = __uint_as_float((unsigned)(win >> 32));
  float mx = outv;
#pragma unroll
  for (int off = 16; off; off >>= 1) mx = fmaxf(mx, __shfl_xor(mx, off, 32));
  const float e = expf(outv - mx);
  float sum = e;
#pragma unroll
  for (int off = 16; off; off >>= 1) sum += __shfl_xor(sum, off, 32);
  if (lane < TOPK) {
    probs[(size_t)r * TOPK + lane] = e / sum;
    pidx [(size_t)r * TOPK + lane] = NN - 1 - (int)(win & 0xFFFFFFFFu);
  }
}

// ---------------------------------------------------------------------------
// K2: gc gather (bf16 src) + residual + LayerNorm1 -> tgt1 (in d_out).
// One block per row m, ALL 8 batches. Thread = (b = tid>>5, h8 = (tid&31)*8):
// per k one bf16x8 (16B) load covers 8 h. LN reduce = width-32 shuffle
// (one batch per half... per 32-lane group), no LDS reduction.
// ---------------------------------------------------------------------------
__global__ __launch_bounds__(256) void k_gather_ln1(
    const unsigned short* __restrict__ s16, const float* __restrict__ tgt,
    const float* __restrict__ probs, const int* __restrict__ pidx,
    const float* __restrict__ lnw, const float* __restrict__ lnb,
    float* __restrict__ out) {
  __shared__ float lp[TOPK];
  __shared__ int li[TOPK];
  const int m = blockIdx.x, tid = threadIdx.x;
  if (tid < TOPK) { lp[tid] = probs[(size_t)m * TOPK + tid]; li[tid] = pidx[(size_t)m * TOPK + tid]; }
  __syncthreads();

  const int b = tid >> 5, h8 = (tid & 31) * 8;
  const unsigned short* sb = s16 + (size_t)b * NN * HH + h8;

  float acc[8] = {0.f, 0.f, 0.f, 0.f, 0.f, 0.f, 0.f, 0.f};
#pragma unroll
  for (int k = 0; k < TOPK; ++k) {
    const bf16x8 v = *reinterpret_cast<const bf16x8*>(sb + (size_t)li[k] * HH);
    const float p = lp[k];
#pragma unroll
    for (int e = 0; e < 8; ++e)
      acc[e] = fmaf(p, bf2f((unsigned short)v[e]), acc[e]);
  }

  // residual
  const size_t obase = ((size_t)b * NN + m) * HH + h8;
  const float4 t0 = *reinterpret_cast<const float4*>(tgt + obase);
  const float4 t1 = *reinterpret_cast<const float4*>(tgt + obase + 4);
  acc[0] += t0.x; acc[1] += t0.y; acc[2] += t0.z; acc[3] += t0.w;
  acc[4] += t1.x; acc[5] += t1.y; acc[6] += t1.z; acc[7] += t1.w;

  // LN over 256 h: 32 lanes x 8 elems, width-32 butterfly
  float s = 0.f, s2 = 0.f;
#pragma unroll
  for (int e = 0; e < 8; ++e) { s += acc[e]; s2 = fmaf(acc[e], acc[e], s2); }
#pragma unroll
  for (int off = 16; off; off >>= 1) {
    s += __shfl_xor(s, off, 32);
    s2 += __shfl_xor(s2, off, 32);
  }
  const float mu = s * (1.f / HH);
  const float var = s2 * (1.f / HH) - mu * mu;
  const float rs = rsqrtf(var + LN_EPS);

  const float4 w0 = *reinterpret_cast<const float4*>(lnw + h8);
  const float4 w1 = *reinterpret_cast<const float4*>(lnw + h8 + 4);
  const float4 c0 = *reinterpret_cast<const float4*>(lnb + h8);
  const float4 c1 = *reinterpret_cast<const float4*>(lnb + h8 + 4);
  float4 o0, o1;
  o0.x = (acc[0] - mu) * rs * w0.x + c0.x;
  o0.y = (acc[1] - mu) * rs * w0.y + c0.y;
  o0.z = (acc[2] - mu) * rs * w0.z + c0.z;
  o0.w = (acc[3] - mu) * rs * w0.w + c0.w;
  o1.x = (acc[4] - mu) * rs * w1.x + c1.x;
  o1.y = (acc[5] - mu) * rs * w1.y + c1.y;
  o1.z = (acc[6] - mu) * rs * w1.z + c1.z;
  o1.w = (acc[7] - mu) * rs * w1.w + c1.w;
  *reinterpret_cast<float4*>(out + obase) = o0;
  *reinterpret_cast<float4*>(out + obase + 4) = o1;
}

// ---------------------------------------------------------------------------
// K5: out = LN2(tgt1 + ff2). tgt1 aliases out (row-exclusive, in-place safe).
// ---------------------------------------------------------------------------
__global__ __launch_bounds__(256) void k_res_ln2(
    const float* tgt1, const float* __restrict__ ff,
    const float* __restrict__ lnw, const float* __restrict__ lnb,
    float* out) {
  __shared__ float red[8];
  const size_t row = blockIdx.x;
  const int tid = threadIdx.x;
  const float x = tgt1[row * HH + tid] + ff[row * HH + tid];
  float s = x, s2 = x * x;
#pragma unroll
  for (int off = 32; off; off >>= 1) { s += __shfl_down(s, off); s2 += __shfl_down(s2, off); }
  const int wid = tid >> 6, lane = tid & 63;
  if (!lane) { red[wid] = s; red[4 + wid] = s2; }
  __syncthreads();
  s  = red[0] + red[1] + red[2] + red[3];
  s2 = red[4] + red[5] + red[6] + red[7];
  const float mu = s * (1.f / HH);
  const float var = s2 * (1.f / HH) - mu * mu;
  const float rs = rsqrtf(var + LN_EPS);
  out[row * HH + tid] = (x - mu) * rs * lnw[tid] + lnb[tid];
}

// ---------------------------------------------------------------------------
extern "C" void kernel_launch(void* const* d_in, const int* in_sizes, int n_in,
                              void* d_out, int out_size, void* d_ws, size_t ws_size,
                              hipStream_t stream) {
  const float* src  = (const float*)d_in[0];
  const float* tgt  = (const float*)d_in[1];
  const float* n1   = (const float*)d_in[2];
  const float* n2   = (const float*)d_in[3];
  const float* w1   = (const float*)d_in[4];
  const float* b1   = (const float*)d_in[5];
  const float* w2   = (const float*)d_in[6];
  const float* b2   = (const float*)d_in[7];
  const float* ln1w = (const float*)d_in[8];
  const float* ln1b = (const float*)d_in[9];
  const float* ln2w = (const float*)d_in[10];
  const float* ln2b = (const float*)d_in[11];
  float* out = (float*)d_out;

  // ws (floats): probs | pidx | region (64 MB) | apack 4MB | bpack 4MB ~73MB
  // region lifetimes (stream-ordered, all safe):
  //   adj [0,64)        written by adjgemm, read by topk
  //   s16 [0,16.8)      written by srcpack AFTER topk, read by gather
  //   ff1 [0,33.5)      written by ffgemm1 AFTER gather
  //   ff2 [33.5,67)     written by ffgemm2 (extends 3MB into apack - dead)
  float* wsf   = (float*)d_ws;
  float* probs = wsf;
  int*   pidx  = (int*)(wsf + (size_t)NN * TOPK);
  float* base  = wsf + 2 * (size_t)NN * TOPK;
  float* adj   = base;
  unsigned short* s16 = (unsigned short*)base;
  float* ff1   = base;
  float* ff2   = base + (size_t)BATCH * NN * HH;
  unsigned short* apack = (unsigned short*)(base + (size_t)NN * NN);
  unsigned short* bpack = apack + (size_t)32 * 16 * 512 * 8;

  dim3 gp(512, 2);
  k_pack<<<gp, 256, 0, stream>>>(n1, n2, apack, bpack);
  k_adjgemm_pk<<<(NN / 128) * (NN / 128), 256, 0, stream>>>(apack, bpack, adj);
  k_topk<<<NN / 4, 256, 0, stream>>>(adj, probs, pidx);

  // src -> bf16 (overlays dead adj)
  k_srcpack<<<(BATCH * NN * HH) / (256 * 8), 256, 0, stream>>>(src, s16);

  k_gather_ln1<<<NN, 256, 0, stream>>>(s16, tgt, probs, pidx, ln1w, ln1b, out);

  const int gemm_grid = (BATCH * NN / 128) * (HH / 128);  // 512
  k_ffgemm_mfma<1><<<gemm_grid, 256, 0, stream>>>(out, w1, b1, ff1);
  k_ffgemm_mfma<0><<<gemm_grid, 256, 0, stream>>>(ff1, w2, b2, ff2);

  k_res_ln2<<<BATCH * NN, 256, 0, stream>>>(out, ff2, ln2w, ln2b, out);
}